// Round 1
// baseline (1911.963 us; speedup 1.0000x reference)
//
#include <hip/hip_runtime.h>
#include <math.h>

#define B_    8
#define T_    2560
#define F_    229
#define C1_   5
#define C2_   11
#define W1_   114   // after first pool
#define W2_   57    // after second pool
#define FEAT  627   // C2_*W2_
#define OF_   88
#define MC_   48
#define G_    8
#define DH_   6
#define K_    31
#define PAD_  15
#define BN_EPS 1e-5f
#define LN_EPS 1e-5f

static inline int cdiv(int a, int b) { return (a + b - 1) / b; }

// ---------------- conv1: 1 -> C1, 3x3 SAME, + bn + relu ----------------
__global__ void conv1_kernel(const float* __restrict__ spec, const float* __restrict__ w,
                             const float* __restrict__ bias, const float* __restrict__ g,
                             const float* __restrict__ bb, const float* __restrict__ m,
                             const float* __restrict__ vv, float* __restrict__ out) {
    int idx = blockIdx.x * blockDim.x + threadIdx.x;
    const int total = B_ * C1_ * T_ * F_;
    if (idx >= total) return;
    int f = idx % F_;
    int t = (idx / F_) % T_;
    int c = (idx / (F_ * T_)) % C1_;
    int b = idx / (F_ * T_ * C1_);
    const float* sp = spec + (size_t)b * T_ * F_;
    const float* wc = w + c * 9;
    float s = bias[c];
#pragma unroll
    for (int dt = 0; dt < 3; ++dt) {
        int tt = t + dt - 1;
        if (tt < 0 || tt >= T_) continue;
        const float* row = sp + (size_t)tt * F_;
#pragma unroll
        for (int df = 0; df < 3; ++df) {
            int ff = f + df - 1;
            if (ff < 0 || ff >= F_) continue;
            s += row[ff] * wc[dt * 3 + df];
        }
    }
    float sc = g[c] * rsqrtf(vv[c] + BN_EPS);
    float y = (s - m[c]) * sc + bb[c];
    out[idx] = fmaxf(y, 0.f);
}

// ------------- conv (CIN->COUT, 3x3 SAME) + bn + relu + maxpool w2 -------------
template <int CIN, int COUT, int WIN>
__global__ void conv_bn_relu_pool_kernel(const float* __restrict__ in, const float* __restrict__ w,
                                         const float* __restrict__ bias, const float* __restrict__ g,
                                         const float* __restrict__ bb, const float* __restrict__ m,
                                         const float* __restrict__ vv, float* __restrict__ out) {
    const int WOUT = WIN / 2;
    int idx = blockIdx.x * blockDim.x + threadIdx.x;
    const int total = B_ * COUT * T_ * WOUT;
    if (idx >= total) return;
    int j = idx % WOUT;
    int t = (idx / WOUT) % T_;
    int c = (idx / (WOUT * T_)) % COUT;
    int b = idx / (WOUT * T_ * COUT);
    float a0 = bias[c], a1 = bias[c];
    for (int ci = 0; ci < CIN; ++ci) {
        const float* base = in + ((size_t)(b * CIN + ci) * T_) * WIN;
        const float* wc = w + (c * CIN + ci) * 9;
#pragma unroll
        for (int dt = 0; dt < 3; ++dt) {
            int tt = t + dt - 1;
            if (tt < 0 || tt >= T_) continue;
            const float* row = base + (size_t)tt * WIN;
#pragma unroll
            for (int dw = 0; dw < 3; ++dw) {
                float wt = wc[dt * 3 + dw];
                int f0 = 2 * j + dw - 1;           // conv position for pool slot 0
                if (f0 >= 0 && f0 < WIN) a0 += row[f0] * wt;
                int f1 = f0 + 1;                   // pool slot 1 (always >= 0)
                if (f1 < WIN) a1 += row[f1] * wt;
            }
        }
    }
    float sc = g[c] * rsqrtf(vv[c] + BN_EPS);
    a0 = fmaxf((a0 - m[c]) * sc + bb[c], 0.f);
    a1 = fmaxf((a1 - m[c]) * sc + bb[c], 0.f);
    out[idx] = fmaxf(a0, a1);
}

// ---------------- FC: (B,T, C2*57) @ fc_w.T + fc_b -> (B,T,88) ----------------
__global__ void fc_kernel(const float* __restrict__ x3p, const float* __restrict__ fw,
                          const float* __restrict__ fb, float* __restrict__ xfc) {
    __shared__ float lds[FEAT];
    int bt = blockIdx.x;          // b*T_ + t
    int b = bt / T_;
    int t = bt % T_;
    for (int i = threadIdx.x; i < FEAT; i += blockDim.x) {
        int c = i / W2_;
        int wp = i % W2_;
        lds[i] = x3p[((size_t)(b * C2_ + c) * T_ + t) * W2_ + wp];
    }
    __syncthreads();
    int o = threadIdx.x;
    if (o < OF_) {
        float acc = fb[o];
        const float* wrow = fw + (size_t)o * FEAT;
        for (int i = 0; i < FEAT; ++i) acc += lds[i] * wrow[i];
        xfc[(size_t)bt * OF_ + o] = acc;
    }
}

// ---------------- QKV: x (B,T,88) -> q,k,v (B,T,48), no bias ----------------
__global__ void qkv_kernel(const float* __restrict__ xfc, const float* __restrict__ wq,
                           const float* __restrict__ wk, const float* __restrict__ wv,
                           float* __restrict__ q, float* __restrict__ k, float* __restrict__ v) {
    __shared__ float lds[OF_];
    int bt = blockIdx.x;
    for (int i = threadIdx.x; i < OF_; i += blockDim.x) lds[i] = xfc[(size_t)bt * OF_ + i];
    __syncthreads();
    int o = threadIdx.x;
    if (o < MC_) {
        float aq = 0.f, ak = 0.f, av = 0.f;
        const float* wq_r = wq + o * OF_;
        const float* wk_r = wk + o * OF_;
        const float* wv_r = wv + o * OF_;
        for (int i = 0; i < OF_; ++i) {
            float x = lds[i];
            aq += x * wq_r[i];
            ak += x * wk_r[i];
            av += x * wv_r[i];
        }
        q[(size_t)bt * MC_ + o] = aq;
        k[(size_t)bt * MC_ + o] = ak;
        v[(size_t)bt * MC_ + o] = av;
    }
}

// ---------------- windowed relative attention ----------------
// one thread per (b,t,g): energy over K=31 taps, softmax, out = attn @ v-window
__global__ void attn_kernel(const float* __restrict__ q, const float* __restrict__ k,
                            const float* __restrict__ v, const float* __restrict__ rel,
                            float* __restrict__ attout, float* __restrict__ aout) {
    int idx = blockIdx.x * blockDim.x + threadIdx.x;
    if (idx >= B_ * T_ * G_) return;
    int g = idx % G_;
    int t = (idx / G_) % T_;
    int b = idx / (G_ * T_);
    int bt = b * T_ + t;
    float qv[DH_];
#pragma unroll
    for (int d = 0; d < DH_; ++d) qv[d] = q[(size_t)bt * MC_ + g * DH_ + d];

    float e[K_];
    float emax = -1e30f;
    for (int kp = 0; kp < K_; ++kp) {
        int tt = t + kp - PAD_;
        bool in = (tt >= 0 && tt < T_);
        const float* kr = in ? (k + ((size_t)(b * T_ + tt) * MC_ + g * DH_)) : nullptr;
        float s = 0.f;
#pragma unroll
        for (int d = 0; d < DH_; ++d) {
            float kvv = in ? kr[d] : 0.f;
            s += qv[d] * (kvv + rel[(g * DH_ + d) * K_ + kp]);
        }
        e[kp] = s;
        emax = fmaxf(emax, s);
    }
    float sum = 0.f;
    for (int kp = 0; kp < K_; ++kp) {
        e[kp] = expf(e[kp] - emax);
        sum += e[kp];
    }
    float inv = 1.f / sum;
    float o[DH_];
#pragma unroll
    for (int d = 0; d < DH_; ++d) o[d] = 0.f;
    for (int kp = 0; kp < K_; ++kp) {
        float a = e[kp] * inv;
        aout[((size_t)bt * G_ + g) * K_ + kp] = a;
        int tt = t + kp - PAD_;
        if (tt >= 0 && tt < T_) {
            const float* vr = v + ((size_t)(b * T_ + tt) * MC_ + g * DH_);
#pragma unroll
            for (int d = 0; d < DH_; ++d) o[d] += a * vr[d];
        }
    }
#pragma unroll
    for (int d = 0; d < DH_; ++d) attout[(size_t)bt * MC_ + g * DH_ + d] = o[d];
}

// ---------------- LayerNorm(48) + linear(48->88) + sigmoid ----------------
__global__ void ln_lin_sig_kernel(const float* __restrict__ ao, const float* __restrict__ lng,
                                  const float* __restrict__ lnb, const float* __restrict__ lw,
                                  const float* __restrict__ lb, float* __restrict__ fp) {
    int idx = blockIdx.x * blockDim.x + threadIdx.x;
    if (idx >= B_ * T_ * OF_) return;
    int o = idx % OF_;
    int bt = idx / OF_;
    const float* row = ao + (size_t)bt * MC_;
    float mu = 0.f;
    for (int c = 0; c < MC_; ++c) mu += row[c];
    mu *= (1.f / MC_);
    float var = 0.f;
    for (int c = 0; c < MC_; ++c) {
        float d = row[c] - mu;
        var += d * d;
    }
    var *= (1.f / MC_);
    float rstd = rsqrtf(var + LN_EPS);
    float acc = lb[o];
    const float* lwr = lw + o * MC_;
    for (int c = 0; c < MC_; ++c) {
        float h = (row[c] - mu) * rstd * lng[c] + lnb[c];
        acc += h * lwr[c];
    }
    fp[idx] = 1.f / (1.f + expf(-acc));
}

extern "C" void kernel_launch(void* const* d_in, const int* in_sizes, int n_in,
                              void* d_out, int out_size, void* d_ws, size_t ws_size,
                              hipStream_t stream) {
    const float* spec = (const float*)d_in[0];
    const float* c1_w = (const float*)d_in[1];
    const float* c1_b = (const float*)d_in[2];
    const float* bn1_g = (const float*)d_in[3];
    const float* bn1_b = (const float*)d_in[4];
    const float* bn1_m = (const float*)d_in[5];
    const float* bn1_v = (const float*)d_in[6];
    const float* c2_w = (const float*)d_in[7];
    const float* c2_b = (const float*)d_in[8];
    const float* bn2_g = (const float*)d_in[9];
    const float* bn2_b = (const float*)d_in[10];
    const float* bn2_m = (const float*)d_in[11];
    const float* bn2_v = (const float*)d_in[12];
    const float* c3_w = (const float*)d_in[13];
    const float* c3_b = (const float*)d_in[14];
    const float* bn3_g = (const float*)d_in[15];
    const float* bn3_b = (const float*)d_in[16];
    const float* bn3_m = (const float*)d_in[17];
    const float* bn3_v = (const float*)d_in[18];
    const float* fc_w = (const float*)d_in[19];
    const float* fc_b = (const float*)d_in[20];
    const float* wq = (const float*)d_in[21];
    const float* wk = (const float*)d_in[22];
    const float* wv = (const float*)d_in[23];
    const float* rel = (const float*)d_in[24];
    const float* ln_g = (const float*)d_in[25];
    const float* ln_b = (const float*)d_in[26];
    const float* lin_w = (const float*)d_in[27];
    const float* lin_b = (const float*)d_in[28];

    // workspace layout (floats)
    const size_t X1_ELEMS = (size_t)B_ * C1_ * T_ * F_;    // 23,449,600  region A
    const size_t X2P_ELEMS = (size_t)B_ * C1_ * T_ * W1_;  // 11,673,600  region B
    const size_t XFC_ELEMS = (size_t)B_ * T_ * OF_;        // 1,802,240
    const size_t QKV_ELEMS = (size_t)B_ * T_ * MC_;        // 983,040

    float* ws = (float*)d_ws;
    float* x1 = ws;                      // region A: x1, later x3p
    float* x3p = ws;
    float* regB = ws + X1_ELEMS;         // region B: x2p, later xfc/q/k/v/attout
    float* x2p = regB;
    float* xfc = regB;
    float* qb = regB + XFC_ELEMS;
    float* kb = qb + QKV_ELEMS;
    float* vb = kb + QKV_ELEMS;
    float* attout = vb + QKV_ELEMS;

    float* frame_pred = (float*)d_out;
    float* a_out = frame_pred + (size_t)B_ * T_ * OF_;

    const int BLK = 256;

    // 1. conv1 + bn + relu -> x1 (B,C1,T,F)
    {
        int total = B_ * C1_ * T_ * F_;
        conv1_kernel<<<cdiv(total, BLK), BLK, 0, stream>>>(spec, c1_w, c1_b, bn1_g, bn1_b,
                                                           bn1_m, bn1_v, x1);
    }
    // 2. conv2 + bn + relu + pool -> x2p (B,C1,T,114)
    {
        int total = B_ * C1_ * T_ * W1_;
        conv_bn_relu_pool_kernel<C1_, C1_, F_><<<cdiv(total, BLK), BLK, 0, stream>>>(
            x1, c2_w, c2_b, bn2_g, bn2_b, bn2_m, bn2_v, x2p);
    }
    // 3. conv3 + bn + relu + pool -> x3p (B,C2,T,57)  (overwrites region A; x1 dead)
    {
        int total = B_ * C2_ * T_ * W2_;
        conv_bn_relu_pool_kernel<C1_, C2_, W1_><<<cdiv(total, BLK), BLK, 0, stream>>>(
            x2p, c3_w, c3_b, bn3_g, bn3_b, bn3_m, bn3_v, x3p);
    }
    // 4. FC -> xfc (B,T,88)   (overwrites region B start; x2p dead)
    fc_kernel<<<B_ * T_, 128, 0, stream>>>(x3p, fc_w, fc_b, xfc);
    // 5. QKV -> q,k,v (B,T,48)
    qkv_kernel<<<B_ * T_, 64, 0, stream>>>(xfc, wq, wk, wv, qb, kb, vb);
    // 6. attention -> attout (B,T,48), a_out (B,T,G,K)
    {
        int total = B_ * T_ * G_;
        attn_kernel<<<cdiv(total, BLK), BLK, 0, stream>>>(qb, kb, vb, rel, attout, a_out);
    }
    // 7. LayerNorm + linear + sigmoid -> frame_pred (B,T,88)
    {
        int total = B_ * T_ * OF_;
        ln_lin_sig_kernel<<<cdiv(total, BLK), BLK, 0, stream>>>(attout, ln_g, ln_b, lin_w,
                                                                lin_b, frame_pred);
    }
}

// Round 2
// 1250.583 us; speedup vs baseline: 1.5289x; 1.5289x over previous
//
#include <hip/hip_runtime.h>
#include <math.h>

#define B_    8
#define T_    2560
#define F_    229
#define C1_   5
#define C2_   11
#define W1_   114   // after first pool
#define W2_   57    // after second pool
#define OF_   88
#define MC_   48
#define G_    8
#define DH_   6
#define K_    31
#define PAD_  15
#define BN_EPS 1e-5f
#define LN_EPS 1e-5f

static inline int cdiv(int a, int b) { return (a + b - 1) / b; }

// ---------------- conv1: 1 -> 5, 3x3 SAME, + bn + relu ----------------
// thread per (b,t,f): load 9 taps once, compute all 5 output channels.
__global__ __launch_bounds__(256) void conv1_kernel(const float* __restrict__ spec,
        const float* __restrict__ w, const float* __restrict__ cb,
        const float* __restrict__ g, const float* __restrict__ bb,
        const float* __restrict__ m, const float* __restrict__ vv,
        float* __restrict__ out) {
    int idx = blockIdx.x * 256 + threadIdx.x;
    if (idx >= B_ * T_ * F_) return;
    int f = idx % F_;
    int t = (idx / F_) % T_;
    int b = idx / (F_ * T_);
    const float* sp = spec + (size_t)b * T_ * F_;
    float tap[3][3];
#pragma unroll
    for (int dt = 0; dt < 3; ++dt) {
        int tt = t + dt - 1;
        bool tv = (tt >= 0 && tt < T_);
#pragma unroll
        for (int df = 0; df < 3; ++df) {
            int ff = f + df - 1;
            tap[dt][df] = (tv && ff >= 0 && ff < F_) ? sp[(size_t)tt * F_ + ff] : 0.f;
        }
    }
#pragma unroll
    for (int co = 0; co < C1_; ++co) {
        float acc = 0.f;
#pragma unroll
        for (int k = 0; k < 9; ++k) acc += tap[k / 3][k % 3] * w[co * 9 + k];
        float scl = g[co] * rsqrtf(vv[co] + BN_EPS);
        float y = (acc + cb[co] - m[co]) * scl + bb[co];
        out[((size_t)(b * C1_ + co) * T_ + t) * F_ + f] = fmaxf(y, 0.f);
    }
}

// ------- conv (CIN->COUT, 3x3 SAME) + bn + relu + maxpool w2, LDS-tiled -------
// block = one (b, t-pair); threads = pooled j; thread computes all COUT chans
// for 2 t values. Input rows t0-1..t0+2 staged in LDS (zero-padded width).
template <int CIN, int COUT, int WIN, int WLDS, int NTHR>
__global__ __launch_bounds__(NTHR) void conv_pool_kernel(const float* __restrict__ in,
        const float* __restrict__ w, const float* __restrict__ cb,
        const float* __restrict__ g, const float* __restrict__ bb,
        const float* __restrict__ m, const float* __restrict__ vv,
        float* __restrict__ out) {
    const int WOUT = WIN / 2;
    __shared__ float tile[4 * CIN * WLDS];          // [row][ci][WLDS], col = f+1
    __shared__ float wl[CIN * 3 * COUT * 4];        // [ci][dt][co][4], dw padded
    __shared__ float scl_s[COUT], shf_s[COUT];
    int t0 = blockIdx.x * 2;
    int b = blockIdx.y;
    int tid = threadIdx.x;
    for (int i = tid; i < 4 * CIN * WLDS; i += NTHR) {
        int wc = i % WLDS;
        int ci = (i / WLDS) % CIN;
        int rr = i / (WLDS * CIN);
        int r = t0 - 1 + rr;
        int f = wc - 1;
        float v = 0.f;
        if (r >= 0 && r < T_ && f >= 0 && f < WIN)
            v = in[((size_t)(b * CIN + ci) * T_ + r) * WIN + f];
        tile[i] = v;
    }
    for (int i = tid; i < CIN * 3 * COUT * 4; i += NTHR) {
        int dw = i & 3;
        int co = (i >> 2) % COUT;
        int dt = (i / (4 * COUT)) % 3;
        int ci = i / (12 * COUT);
        wl[i] = (dw < 3) ? w[(co * CIN + ci) * 9 + dt * 3 + dw] : 0.f;
    }
    if (tid < COUT) {
        float s = g[tid] * rsqrtf(vv[tid] + BN_EPS);
        scl_s[tid] = s;
        shf_s[tid] = (cb[tid] - m[tid]) * s + bb[tid];
    }
    __syncthreads();
    int j = tid;
    if (j >= WOUT) return;
    float a0[2][COUT], a1[2][COUT];
#pragma unroll
    for (int tt = 0; tt < 2; ++tt)
#pragma unroll
        for (int co = 0; co < COUT; ++co) { a0[tt][co] = 0.f; a1[tt][co] = 0.f; }
#pragma unroll
    for (int ci = 0; ci < CIN; ++ci) {
        float tp4[4][4];
#pragma unroll
        for (int rr = 0; rr < 4; ++rr) {
            const float* p = &tile[(rr * CIN + ci) * WLDS + 2 * j];
            float2 x0 = *(const float2*)p;
            float2 x1 = *(const float2*)(p + 2);
            tp4[rr][0] = x0.x; tp4[rr][1] = x0.y; tp4[rr][2] = x1.x; tp4[rr][3] = x1.y;
        }
#pragma unroll
        for (int dt = 0; dt < 3; ++dt) {
#pragma unroll
            for (int co = 0; co < COUT; ++co) {
                const float4 wv = *(const float4*)&wl[((ci * 3 + dt) * COUT + co) * 4];
#pragma unroll
                for (int tt = 0; tt < 2; ++tt) {
                    int rr = dt + tt;
                    a0[tt][co] += tp4[rr][0] * wv.x + tp4[rr][1] * wv.y + tp4[rr][2] * wv.z;
                    a1[tt][co] += tp4[rr][1] * wv.x + tp4[rr][2] * wv.y + tp4[rr][3] * wv.z;
                }
            }
        }
    }
#pragma unroll
    for (int co = 0; co < COUT; ++co) {
        float s = scl_s[co], sh = shf_s[co];
#pragma unroll
        for (int tt = 0; tt < 2; ++tt) {
            float y0 = fmaxf(a0[tt][co] * s + sh, 0.f);
            float y1 = fmaxf(a1[tt][co] * s + sh, 0.f);
            out[((size_t)(b * COUT + co) * T_ + t0 + tt) * WOUT + j] = fmaxf(y0, y1);
        }
    }
}

// -------- W' = [wq;wk;wv] @ fc_w (144 x 627), b' = [wq;wk;wv] @ fc_b --------
__global__ __launch_bounds__(256) void wprime_kernel(const float* __restrict__ fc_w,
        const float* __restrict__ fc_b, const float* __restrict__ wq,
        const float* __restrict__ wk, const float* __restrict__ wv,
        float* __restrict__ wp, float* __restrict__ bp) {
    int idx = blockIdx.x * 256 + threadIdx.x;
    if (idx >= 144 * 628) return;
    int o = idx / 628;
    int kk = idx % 628;
    const float* Wrow = (o < 48) ? (wq + o * 88) : (o < 96) ? (wk + (o - 48) * 88)
                                                            : (wv + (o - 96) * 88);
    if (kk < 627) {
        float s = 0.f;
        for (int i = 0; i < 88; ++i) s += Wrow[i] * fc_w[(size_t)i * 627 + kk];
        wp[(size_t)o * 627 + kk] = s;
    } else {
        float s = 0.f;
        for (int i = 0; i < 88; ++i) s += Wrow[i] * fc_b[i];
        bp[o] = s;
    }
}

// -------- fused FC+QKV GEMM: Q[bt][144] = feat[bt][627] @ W'^T + b' --------
// block 192 thr: 64 t-rows x 144 outs, k-chunks of 57 (= one conv channel).
// thread tile 8t x 6o, interleaved (r*8+ti, c*24+oi) to avoid bank conflicts.
__global__ __launch_bounds__(192) void fc_qkv_kernel(const float* __restrict__ x3p,
        const float* __restrict__ wp, const float* __restrict__ bp,
        float* __restrict__ Q) {
    __shared__ float Xt[64 * 60];
    __shared__ float Wt[144 * 60];
    int b = blockIdx.y;
    int t0 = blockIdx.x * 64;
    int tid = threadIdx.x;
    int oi = tid % 24;
    int ti = tid / 24;
    float acc[8][6];
#pragma unroll
    for (int r = 0; r < 8; ++r)
#pragma unroll
        for (int c = 0; c < 6; ++c) acc[r][c] = 0.f;
    for (int ci = 0; ci < 11; ++ci) {
        for (int i = tid; i < 64 * 60; i += 192) {
            int tt = i / 60, wc = i % 60;
            Xt[i] = (wc < 57) ? x3p[((size_t)(b * 11 + ci) * T_ + t0 + tt) * 57 + wc] : 0.f;
        }
        for (int i = tid; i < 144 * 60; i += 192) {
            int o = i / 60, wc = i % 60;
            Wt[i] = (wc < 57) ? wp[(size_t)o * 627 + ci * 57 + wc] : 0.f;
        }
        __syncthreads();
#pragma unroll
        for (int kk = 0; kk < 15; ++kk) {
            float4 xv[8], wv[6];
#pragma unroll
            for (int r = 0; r < 8; ++r) xv[r] = *(const float4*)&Xt[(r * 8 + ti) * 60 + kk * 4];
#pragma unroll
            for (int c = 0; c < 6; ++c) wv[c] = *(const float4*)&Wt[(c * 24 + oi) * 60 + kk * 4];
#pragma unroll
            for (int r = 0; r < 8; ++r)
#pragma unroll
                for (int c = 0; c < 6; ++c)
                    acc[r][c] += xv[r].x * wv[c].x + xv[r].y * wv[c].y +
                                 xv[r].z * wv[c].z + xv[r].w * wv[c].w;
        }
        __syncthreads();
    }
#pragma unroll
    for (int c = 0; c < 6; ++c) {
        int o = c * 24 + oi;
        float bias = bp[o];
#pragma unroll
        for (int r = 0; r < 8; ++r) {
            int t = t0 + r * 8 + ti;
            Q[((size_t)b * T_ + t) * 144 + o] = acc[r][c] + bias;
        }
    }
}

// ---------------- windowed relative attention, LDS-tiled ----------------
// block per (b, 64-t tile): stage q/k/v rows [t0-15, t0+78] + rel^T in LDS.
__global__ __launch_bounds__(256) void attn_kernel(const float* __restrict__ Q,
        const float* __restrict__ rel, float* __restrict__ attout,
        float* __restrict__ aout) {
    __shared__ float kv[94 * 144];
    __shared__ float relT[31 * 48];
    int b = blockIdx.y;
    int t0 = blockIdx.x * 64;
    int tid = threadIdx.x;
    for (int i = tid; i < 94 * 144; i += 256) {
        int rr = i / 144, c = i % 144;
        int r = t0 - 15 + rr;
        kv[i] = (r >= 0 && r < T_) ? Q[((size_t)b * T_ + r) * 144 + c] : 0.f;
    }
    for (int i = tid; i < 31 * 48; i += 256) {
        int kp = i / 48, jj = i % 48;
        relT[i] = rel[jj * 31 + kp];
    }
    __syncthreads();
    for (int it = tid; it < 512; it += 256) {
        int g = it & 7;
        int tl = it >> 3;
        const float* qp = &kv[(tl + 15) * 144 + g * 6];
        float q0 = qp[0], q1 = qp[1], q2 = qp[2], q3 = qp[3], q4 = qp[4], q5 = qp[5];
        float e[31];
        float emax = -1e30f;
#pragma unroll
        for (int kp = 0; kp < 31; ++kp) {
            const float* kr = &kv[(tl + kp) * 144 + 48 + g * 6];
            const float* rr = &relT[kp * 48 + g * 6];
            float s = q0 * (kr[0] + rr[0]) + q1 * (kr[1] + rr[1]) + q2 * (kr[2] + rr[2]) +
                      q3 * (kr[3] + rr[3]) + q4 * (kr[4] + rr[4]) + q5 * (kr[5] + rr[5]);
            e[kp] = s;
            emax = fmaxf(emax, s);
        }
        float sum = 0.f;
#pragma unroll
        for (int kp = 0; kp < 31; ++kp) { e[kp] = __expf(e[kp] - emax); sum += e[kp]; }
        float inv = 1.f / sum;
        float o0 = 0, o1 = 0, o2 = 0, o3 = 0, o4 = 0, o5 = 0;
        int t = t0 + tl;
        float* ap = &aout[(((size_t)b * T_ + t) * 8 + g) * 31];
#pragma unroll
        for (int kp = 0; kp < 31; ++kp) {
            float a = e[kp] * inv;
            ap[kp] = a;
            const float* vr = &kv[(tl + kp) * 144 + 96 + g * 6];
            o0 += a * vr[0]; o1 += a * vr[1]; o2 += a * vr[2];
            o3 += a * vr[3]; o4 += a * vr[4]; o5 += a * vr[5];
        }
        float* op = &attout[((size_t)b * T_ + t) * 48 + g * 6];
        op[0] = o0; op[1] = o1; op[2] = o2; op[3] = o3; op[4] = o4; op[5] = o5;
    }
}

// ---------- LayerNorm(48) + linear(48->88) + sigmoid, 32 rows/block ----------
__global__ __launch_bounds__(256) void ln_kernel(const float* __restrict__ att,
        const float* __restrict__ lng, const float* __restrict__ lnb,
        const float* __restrict__ lw, const float* __restrict__ lb,
        float* __restrict__ fp) {
    __shared__ float xr[32 * 48];
    __shared__ float wl[88 * 48];
    __shared__ float mus[32], rss[32], gs[48], bs[48], lbs[88];
    int row0 = blockIdx.x * 32;
    int tid = threadIdx.x;
    for (int i = tid; i < 32 * 48; i += 256) xr[i] = att[(size_t)row0 * 48 + i];
    for (int i = tid; i < 88 * 48; i += 256) wl[i] = lw[i];
    if (tid < 48) { gs[tid] = lng[tid]; bs[tid] = lnb[tid]; }
    if (tid < 88) lbs[tid] = lb[tid];
    __syncthreads();
    if (tid < 32) {
        float s = 0.f;
        for (int c = 0; c < 48; ++c) s += xr[tid * 48 + c];
        float mu = s * (1.f / 48.f);
        float v2 = 0.f;
        for (int c = 0; c < 48; ++c) { float d = xr[tid * 48 + c] - mu; v2 += d * d; }
        mus[tid] = mu;
        rss[tid] = rsqrtf(v2 * (1.f / 48.f) + LN_EPS);
    }
    __syncthreads();
    for (int i = tid; i < 32 * 48; i += 256) {
        int r = i / 48, c = i % 48;
        xr[i] = (xr[i] - mus[r]) * rss[r] * gs[c] + bs[c];
    }
    __syncthreads();
    for (int k = 0; k < 11; ++k) {
        int cid = k * 256 + tid;
        int o = cid % 88, r = cid / 88;
        const float* xp = &xr[r * 48];
        const float* wpp = &wl[o * 48];
        float s = lbs[o];
#pragma unroll
        for (int c = 0; c < 48; c += 4) {
            float4 xv = *(const float4*)&xp[c];
            float4 wv = *(const float4*)&wpp[c];
            s += xv.x * wv.x + xv.y * wv.y + xv.z * wv.z + xv.w * wv.w;
        }
        fp[(size_t)row0 * 88 + cid] = 1.f / (1.f + __expf(-s));
    }
}

extern "C" void kernel_launch(void* const* d_in, const int* in_sizes, int n_in,
                              void* d_out, int out_size, void* d_ws, size_t ws_size,
                              hipStream_t stream) {
    const float* spec = (const float*)d_in[0];
    const float* c1_w = (const float*)d_in[1];
    const float* c1_b = (const float*)d_in[2];
    const float* bn1_g = (const float*)d_in[3];
    const float* bn1_b = (const float*)d_in[4];
    const float* bn1_m = (const float*)d_in[5];
    const float* bn1_v = (const float*)d_in[6];
    const float* c2_w = (const float*)d_in[7];
    const float* c2_b = (const float*)d_in[8];
    const float* bn2_g = (const float*)d_in[9];
    const float* bn2_b = (const float*)d_in[10];
    const float* bn2_m = (const float*)d_in[11];
    const float* bn2_v = (const float*)d_in[12];
    const float* c3_w = (const float*)d_in[13];
    const float* c3_b = (const float*)d_in[14];
    const float* bn3_g = (const float*)d_in[15];
    const float* bn3_b = (const float*)d_in[16];
    const float* bn3_m = (const float*)d_in[17];
    const float* bn3_v = (const float*)d_in[18];
    const float* fc_w = (const float*)d_in[19];
    const float* fc_b = (const float*)d_in[20];
    const float* wq = (const float*)d_in[21];
    const float* wk = (const float*)d_in[22];
    const float* wv = (const float*)d_in[23];
    const float* rel = (const float*)d_in[24];
    const float* ln_g = (const float*)d_in[25];
    const float* ln_b = (const float*)d_in[26];
    const float* lin_w = (const float*)d_in[27];
    const float* lin_b = (const float*)d_in[28];

    // workspace layout (floats):
    // region A [0, 23449600): x1; later x3p [0,12840960) + W' at 14000000
    // region B [23449600, 35123200): x2p; later Q [0,2949120) + attout at +3000000
    const size_t X1_ELEMS = (size_t)B_ * C1_ * T_ * F_;  // 23,449,600
    float* ws = (float*)d_ws;
    float* x1 = ws;
    float* x3p = ws;
    float* wp = ws + 14000000;          // 144*627 = 90,288
    float* bp = wp + 144 * 627;         // 144
    float* regB = ws + X1_ELEMS;
    float* x2p = regB;                  // 11,673,600
    float* Qb = regB;                   // 20480*144 = 2,949,120 (x2p dead by then)
    float* attout = regB + 3000000;     // 983,040

    float* frame_pred = (float*)d_out;
    float* a_out = frame_pred + (size_t)B_ * T_ * OF_;

    // 1. conv1 + bn + relu -> x1 (B,5,T,229)
    conv1_kernel<<<cdiv(B_ * T_ * F_, 256), 256, 0, stream>>>(spec, c1_w, c1_b, bn1_g,
                                                              bn1_b, bn1_m, bn1_v, x1);
    // 2. conv2 + bn + relu + pool -> x2p (B,5,T,114)
    conv_pool_kernel<C1_, C1_, F_, 232, 128><<<dim3(T_ / 2, B_), 128, 0, stream>>>(
        x1, c2_w, c2_b, bn2_g, bn2_b, bn2_m, bn2_v, x2p);
    // 3. W' (after conv2: x1 region reused for W')
    wprime_kernel<<<cdiv(144 * 628, 256), 256, 0, stream>>>(fc_w, fc_b, wq, wk, wv, wp, bp);
    // 4. conv3 + bn + relu + pool -> x3p (B,11,T,57)
    conv_pool_kernel<C1_, C2_, W1_, 120, 64><<<dim3(T_ / 2, B_), 64, 0, stream>>>(
        x2p, c3_w, c3_b, bn3_g, bn3_b, bn3_m, bn3_v, x3p);
    // 5. fused FC+QKV -> Qb (B*T,144)
    fc_qkv_kernel<<<dim3(T_ / 64, B_), 192, 0, stream>>>(x3p, wp, bp, Qb);
    // 6. attention -> attout (B*T,48), a_out (B,T,8,31)
    attn_kernel<<<dim3(T_ / 64, B_), 256, 0, stream>>>(Qb, rel, attout, a_out);
    // 7. LN + linear + sigmoid -> frame_pred (B,T,88)
    ln_kernel<<<(B_ * T_) / 32, 256, 0, stream>>>(attout, ln_g, ln_b, lin_w, lin_b,
                                                  frame_pred);
}

// Round 3
// 890.096 us; speedup vs baseline: 2.1480x; 1.4050x over previous
//
#include <hip/hip_runtime.h>
#include <math.h>

#define B_    8
#define T_    2560
#define F_    229
#define C1_   5
#define C2_   11
#define W1_   114   // after first pool
#define W2_   57    // after second pool
#define OF_   88
#define MC_   48
#define G_    8
#define DH_   6
#define K_    31
#define PAD_  15
#define BN_EPS 1e-5f
#define LN_EPS 1e-5f

static inline int cdiv(int a, int b) { return (a + b - 1) / b; }

// ---------------- conv1: 1 -> 5, 3x3 SAME, + bn + relu ----------------
__global__ __launch_bounds__(256) void conv1_kernel(const float* __restrict__ spec,
        const float* __restrict__ w, const float* __restrict__ cb,
        const float* __restrict__ g, const float* __restrict__ bb,
        const float* __restrict__ m, const float* __restrict__ vv,
        float* __restrict__ out) {
    int idx = blockIdx.x * 256 + threadIdx.x;
    if (idx >= B_ * T_ * F_) return;
    int f = idx % F_;
    int t = (idx / F_) % T_;
    int b = idx / (F_ * T_);
    const float* sp = spec + (size_t)b * T_ * F_;
    float tap[3][3];
#pragma unroll
    for (int dt = 0; dt < 3; ++dt) {
        int tt = t + dt - 1;
        bool tv = (tt >= 0 && tt < T_);
#pragma unroll
        for (int df = 0; df < 3; ++df) {
            int ff = f + df - 1;
            tap[dt][df] = (tv && ff >= 0 && ff < F_) ? sp[(size_t)tt * F_ + ff] : 0.f;
        }
    }
#pragma unroll
    for (int co = 0; co < C1_; ++co) {
        float acc = 0.f;
#pragma unroll
        for (int k = 0; k < 9; ++k) acc += tap[k / 3][k % 3] * w[co * 9 + k];
        float scl = g[co] * rsqrtf(vv[co] + BN_EPS);
        float y = (acc + cb[co] - m[co]) * scl + bb[co];
        out[((size_t)(b * C1_ + co) * T_ + t) * F_ + f] = fmaxf(y, 0.f);
    }
}

// ------- conv (CIN->COUT, 3x3 SAME) + bn + relu + maxpool w2, LDS-tiled -------
template <int CIN, int COUT, int WIN, int WLDS, int NTHR>
__global__ __launch_bounds__(NTHR) void conv_pool_kernel(const float* __restrict__ in,
        const float* __restrict__ w, const float* __restrict__ cb,
        const float* __restrict__ g, const float* __restrict__ bb,
        const float* __restrict__ m, const float* __restrict__ vv,
        float* __restrict__ out) {
    const int WOUT = WIN / 2;
    __shared__ float tile[4 * CIN * WLDS];          // [row][ci][WLDS], col = f+1
    __shared__ float wl[CIN * 3 * COUT * 4];        // [ci][dt][co][4], dw padded
    __shared__ float scl_s[COUT], shf_s[COUT];
    int t0 = blockIdx.x * 2;
    int b = blockIdx.y;
    int tid = threadIdx.x;
    for (int i = tid; i < 4 * CIN * WLDS; i += NTHR) {
        int wc = i % WLDS;
        int ci = (i / WLDS) % CIN;
        int rr = i / (WLDS * CIN);
        int r = t0 - 1 + rr;
        int f = wc - 1;
        float v = 0.f;
        if (r >= 0 && r < T_ && f >= 0 && f < WIN)
            v = in[((size_t)(b * CIN + ci) * T_ + r) * WIN + f];
        tile[i] = v;
    }
    for (int i = tid; i < CIN * 3 * COUT * 4; i += NTHR) {
        int dw = i & 3;
        int co = (i >> 2) % COUT;
        int dt = (i / (4 * COUT)) % 3;
        int ci = i / (12 * COUT);
        wl[i] = (dw < 3) ? w[(co * CIN + ci) * 9 + dt * 3 + dw] : 0.f;
    }
    if (tid < COUT) {
        float s = g[tid] * rsqrtf(vv[tid] + BN_EPS);
        scl_s[tid] = s;
        shf_s[tid] = (cb[tid] - m[tid]) * s + bb[tid];
    }
    __syncthreads();
    int j = tid;
    if (j >= WOUT) return;
    float a0[2][COUT], a1[2][COUT];
#pragma unroll
    for (int tt = 0; tt < 2; ++tt)
#pragma unroll
        for (int co = 0; co < COUT; ++co) { a0[tt][co] = 0.f; a1[tt][co] = 0.f; }
#pragma unroll
    for (int ci = 0; ci < CIN; ++ci) {
        float tp4[4][4];
#pragma unroll
        for (int rr = 0; rr < 4; ++rr) {
            const float* p = &tile[(rr * CIN + ci) * WLDS + 2 * j];
            float2 x0 = *(const float2*)p;
            float2 x1 = *(const float2*)(p + 2);
            tp4[rr][0] = x0.x; tp4[rr][1] = x0.y; tp4[rr][2] = x1.x; tp4[rr][3] = x1.y;
        }
#pragma unroll
        for (int dt = 0; dt < 3; ++dt) {
#pragma unroll
            for (int co = 0; co < COUT; ++co) {
                const float4 wv = *(const float4*)&wl[((ci * 3 + dt) * COUT + co) * 4];
#pragma unroll
                for (int tt = 0; tt < 2; ++tt) {
                    int rr = dt + tt;
                    a0[tt][co] += tp4[rr][0] * wv.x + tp4[rr][1] * wv.y + tp4[rr][2] * wv.z;
                    a1[tt][co] += tp4[rr][1] * wv.x + tp4[rr][2] * wv.y + tp4[rr][3] * wv.z;
                }
            }
        }
    }
#pragma unroll
    for (int co = 0; co < COUT; ++co) {
        float s = scl_s[co], sh = shf_s[co];
#pragma unroll
        for (int tt = 0; tt < 2; ++tt) {
            float y0 = fmaxf(a0[tt][co] * s + sh, 0.f);
            float y1 = fmaxf(a1[tt][co] * s + sh, 0.f);
            out[((size_t)(b * COUT + co) * T_ + t0 + tt) * WOUT + j] = fmaxf(y0, y1);
        }
    }
}

// -------- W' = [wq;wk;wv] @ fc_w (144 x 627), b' = [wq;wk;wv] @ fc_b --------
__global__ __launch_bounds__(256) void wprime_kernel(const float* __restrict__ fc_w,
        const float* __restrict__ fc_b, const float* __restrict__ wq,
        const float* __restrict__ wk, const float* __restrict__ wv,
        float* __restrict__ wp, float* __restrict__ bp) {
    int idx = blockIdx.x * 256 + threadIdx.x;
    if (idx >= 144 * 628) return;
    int o = idx / 628;
    int kk = idx % 628;
    const float* Wrow = (o < 48) ? (wq + o * 88) : (o < 96) ? (wk + (o - 48) * 88)
                                                            : (wv + (o - 96) * 88);
    if (kk < 627) {
        float s = 0.f;
        for (int i = 0; i < 88; ++i) s += Wrow[i] * fc_w[(size_t)i * 627 + kk];
        wp[(size_t)o * 627 + kk] = s;
    } else {
        float s = 0.f;
        for (int i = 0; i < 88; ++i) s += Wrow[i] * fc_b[i];
        bp[o] = s;
    }
}

// -------- fused FC+QKV GEMM: Q[bt][144] = feat[bt][627] @ W'^T + b' --------
// M-tile 32, N=144, K chunks of 57 (one conv channel). 256 thr, thread tile
// 2t x 9o (acc 18 regs, xv 8, wv 36 -> no spill). grid 640 blocks.
__global__ __launch_bounds__(256) void fc_qkv_kernel(const float* __restrict__ x3p,
        const float* __restrict__ wp, const float* __restrict__ bp,
        float* __restrict__ Q) {
    __shared__ float Xt[32 * 60];
    __shared__ float Wt[144 * 60];
    int b = blockIdx.y;
    int t0 = blockIdx.x * 32;
    int tid = threadIdx.x;
    int oi = tid & 15;          // output lane 0..15
    int ti = tid >> 4;          // row lane 0..15
    float acc[2][9];
#pragma unroll
    for (int r = 0; r < 2; ++r)
#pragma unroll
        for (int c = 0; c < 9; ++c) acc[r][c] = 0.f;
    for (int ci = 0; ci < 11; ++ci) {
        for (int i = tid; i < 32 * 60; i += 256) {
            int tt = i / 60, wc = i % 60;
            Xt[i] = (wc < 57) ? x3p[((size_t)(b * 11 + ci) * T_ + t0 + tt) * 57 + wc] : 0.f;
        }
        for (int i = tid; i < 144 * 60; i += 256) {
            int o = i / 60, wc = i % 60;
            Wt[i] = (wc < 57) ? wp[(size_t)o * 627 + ci * 57 + wc] : 0.f;
        }
        __syncthreads();
#pragma unroll
        for (int kk = 0; kk < 15; ++kk) {
            float4 xv[2], wv[9];
#pragma unroll
            for (int r = 0; r < 2; ++r)
                xv[r] = *(const float4*)&Xt[(r * 16 + ti) * 60 + kk * 4];
#pragma unroll
            for (int c = 0; c < 9; ++c)
                wv[c] = *(const float4*)&Wt[(c * 16 + oi) * 60 + kk * 4];
#pragma unroll
            for (int r = 0; r < 2; ++r)
#pragma unroll
                for (int c = 0; c < 9; ++c)
                    acc[r][c] += xv[r].x * wv[c].x + xv[r].y * wv[c].y +
                                 xv[r].z * wv[c].z + xv[r].w * wv[c].w;
        }
        __syncthreads();
    }
#pragma unroll
    for (int c = 0; c < 9; ++c) {
        int o = c * 16 + oi;
        float bias = bp[o];
#pragma unroll
        for (int r = 0; r < 2; ++r) {
            int t = t0 + r * 16 + ti;
            Q[((size_t)b * T_ + t) * 144 + o] = acc[r][c] + bias;
        }
    }
}

// ---------------- windowed relative attention, LDS-tiled ----------------
__global__ __launch_bounds__(256) void attn_kernel(const float* __restrict__ Q,
        const float* __restrict__ rel, float* __restrict__ attout,
        float* __restrict__ aout) {
    __shared__ float kv[94 * 144];
    __shared__ float relT[31 * 48];
    int b = blockIdx.y;
    int t0 = blockIdx.x * 64;
    int tid = threadIdx.x;
    for (int i = tid; i < 94 * 144; i += 256) {
        int rr = i / 144, c = i % 144;
        int r = t0 - 15 + rr;
        kv[i] = (r >= 0 && r < T_) ? Q[((size_t)b * T_ + r) * 144 + c] : 0.f;
    }
    for (int i = tid; i < 31 * 48; i += 256) {
        int kp = i / 48, jj = i % 48;
        relT[i] = rel[jj * 31 + kp];
    }
    __syncthreads();
    for (int it = tid; it < 512; it += 256) {
        int g = it & 7;
        int tl = it >> 3;
        const float* qp = &kv[(tl + 15) * 144 + g * 6];
        float q0 = qp[0], q1 = qp[1], q2 = qp[2], q3 = qp[3], q4 = qp[4], q5 = qp[5];
        float e[31];
        float emax = -1e30f;
#pragma unroll
        for (int kp = 0; kp < 31; ++kp) {
            const float* kr = &kv[(tl + kp) * 144 + 48 + g * 6];
            const float* rr = &relT[kp * 48 + g * 6];
            float s = q0 * (kr[0] + rr[0]) + q1 * (kr[1] + rr[1]) + q2 * (kr[2] + rr[2]) +
                      q3 * (kr[3] + rr[3]) + q4 * (kr[4] + rr[4]) + q5 * (kr[5] + rr[5]);
            e[kp] = s;
            emax = fmaxf(emax, s);
        }
        float sum = 0.f;
#pragma unroll
        for (int kp = 0; kp < 31; ++kp) { e[kp] = __expf(e[kp] - emax); sum += e[kp]; }
        float inv = 1.f / sum;
        float o0 = 0, o1 = 0, o2 = 0, o3 = 0, o4 = 0, o5 = 0;
        int t = t0 + tl;
        float* ap = &aout[(((size_t)b * T_ + t) * 8 + g) * 31];
#pragma unroll
        for (int kp = 0; kp < 31; ++kp) {
            float a = e[kp] * inv;
            ap[kp] = a;
            const float* vr = &kv[(tl + kp) * 144 + 96 + g * 6];
            o0 += a * vr[0]; o1 += a * vr[1]; o2 += a * vr[2];
            o3 += a * vr[3]; o4 += a * vr[4]; o5 += a * vr[5];
        }
        float* op = &attout[((size_t)b * T_ + t) * 48 + g * 6];
        op[0] = o0; op[1] = o1; op[2] = o2; op[3] = o3; op[4] = o4; op[5] = o5;
    }
}

// ---------- LayerNorm(48) + linear(48->88) + sigmoid, 32 rows/block ----------
__global__ __launch_bounds__(256) void ln_kernel(const float* __restrict__ att,
        const float* __restrict__ lng, const float* __restrict__ lnb,
        const float* __restrict__ lw, const float* __restrict__ lb,
        float* __restrict__ fp) {
    __shared__ float xr[32 * 48];
    __shared__ float wl[88 * 48];
    __shared__ float mus[32], rss[32], gs[48], bs[48], lbs[88];
    int row0 = blockIdx.x * 32;
    int tid = threadIdx.x;
    for (int i = tid; i < 32 * 48; i += 256) xr[i] = att[(size_t)row0 * 48 + i];
    for (int i = tid; i < 88 * 48; i += 256) wl[i] = lw[i];
    if (tid < 48) { gs[tid] = lng[tid]; bs[tid] = lnb[tid]; }
    if (tid < 88) lbs[tid] = lb[tid];
    __syncthreads();
    if (tid < 32) {
        float s = 0.f;
        for (int c = 0; c < 48; ++c) s += xr[tid * 48 + c];
        float mu = s * (1.f / 48.f);
        float v2 = 0.f;
        for (int c = 0; c < 48; ++c) { float d = xr[tid * 48 + c] - mu; v2 += d * d; }
        mus[tid] = mu;
        rss[tid] = rsqrtf(v2 * (1.f / 48.f) + LN_EPS);
    }
    __syncthreads();
    for (int i = tid; i < 32 * 48; i += 256) {
        int r = i / 48, c = i % 48;
        xr[i] = (xr[i] - mus[r]) * rss[r] * gs[c] + bs[c];
    }
    __syncthreads();
    for (int k = 0; k < 11; ++k) {
        int cid = k * 256 + tid;
        int o = cid % 88, r = cid / 88;
        const float* xp = &xr[r * 48];
        const float* wpp = &wl[o * 48];
        float s = lbs[o];
#pragma unroll
        for (int c = 0; c < 48; c += 4) {
            float4 xv = *(const float4*)&xp[c];
            float4 wv = *(const float4*)&wpp[c];
            s += xv.x * wv.x + xv.y * wv.y + xv.z * wv.z + xv.w * wv.w;
        }
        fp[(size_t)row0 * 88 + cid] = 1.f / (1.f + __expf(-s));
    }
}

extern "C" void kernel_launch(void* const* d_in, const int* in_sizes, int n_in,
                              void* d_out, int out_size, void* d_ws, size_t ws_size,
                              hipStream_t stream) {
    const float* spec = (const float*)d_in[0];
    const float* c1_w = (const float*)d_in[1];
    const float* c1_b = (const float*)d_in[2];
    const float* bn1_g = (const float*)d_in[3];
    const float* bn1_b = (const float*)d_in[4];
    const float* bn1_m = (const float*)d_in[5];
    const float* bn1_v = (const float*)d_in[6];
    const float* c2_w = (const float*)d_in[7];
    const float* c2_b = (const float*)d_in[8];
    const float* bn2_g = (const float*)d_in[9];
    const float* bn2_b = (const float*)d_in[10];
    const float* bn2_m = (const float*)d_in[11];
    const float* bn2_v = (const float*)d_in[12];
    const float* c3_w = (const float*)d_in[13];
    const float* c3_b = (const float*)d_in[14];
    const float* bn3_g = (const float*)d_in[15];
    const float* bn3_b = (const float*)d_in[16];
    const float* bn3_m = (const float*)d_in[17];
    const float* bn3_v = (const float*)d_in[18];
    const float* fc_w = (const float*)d_in[19];
    const float* fc_b = (const float*)d_in[20];
    const float* wq = (const float*)d_in[21];
    const float* wk = (const float*)d_in[22];
    const float* wv = (const float*)d_in[23];
    const float* rel = (const float*)d_in[24];
    const float* ln_g = (const float*)d_in[25];
    const float* ln_b = (const float*)d_in[26];
    const float* lin_w = (const float*)d_in[27];
    const float* lin_b = (const float*)d_in[28];

    const size_t X1_ELEMS = (size_t)B_ * C1_ * T_ * F_;  // 23,449,600
    float* ws = (float*)d_ws;
    float* x1 = ws;
    float* x3p = ws;
    float* wp = ws + 14000000;          // 144*627 = 90,288
    float* bp = wp + 144 * 627;         // 144
    float* regB = ws + X1_ELEMS;
    float* x2p = regB;                  // 11,673,600
    float* Qb = regB;                   // 20480*144 = 2,949,120 (x2p dead by then)
    float* attout = regB + 3000000;     // 983,040

    float* frame_pred = (float*)d_out;
    float* a_out = frame_pred + (size_t)B_ * T_ * OF_;

    // 1. conv1 + bn + relu -> x1 (B,5,T,229)
    conv1_kernel<<<cdiv(B_ * T_ * F_, 256), 256, 0, stream>>>(spec, c1_w, c1_b, bn1_g,
                                                              bn1_b, bn1_m, bn1_v, x1);
    // 2. conv2 + bn + relu + pool -> x2p (B,5,T,114)
    conv_pool_kernel<C1_, C1_, F_, 232, 128><<<dim3(T_ / 2, B_), 128, 0, stream>>>(
        x1, c2_w, c2_b, bn2_g, bn2_b, bn2_m, bn2_v, x2p);
    // 3. W' (x1 region reused for W' after conv2)
    wprime_kernel<<<cdiv(144 * 628, 256), 256, 0, stream>>>(fc_w, fc_b, wq, wk, wv, wp, bp);
    // 4. conv3 + bn + relu + pool -> x3p (B,11,T,57)
    conv_pool_kernel<C1_, C2_, W1_, 120, 64><<<dim3(T_ / 2, B_), 64, 0, stream>>>(
        x2p, c3_w, c3_b, bn3_g, bn3_b, bn3_m, bn3_v, x3p);
    // 5. fused FC+QKV -> Qb (B*T,144)
    fc_qkv_kernel<<<dim3(T_ / 32, B_), 256, 0, stream>>>(x3p, wp, bp, Qb);
    // 6. attention -> attout (B*T,48), a_out (B,T,8,31)
    attn_kernel<<<dim3(T_ / 64, B_), 256, 0, stream>>>(Qb, rel, attout, a_out);
    // 7. LN + linear + sigmoid -> frame_pred (B,T,88)
    ln_kernel<<<(B_ * T_) / 32, 256, 0, stream>>>(attout, ln_g, ln_b, lin_w, lin_b,
                                                  frame_pred);
}

// Round 4
// 477.982 us; speedup vs baseline: 4.0001x; 1.8622x over previous
//
#include <hip/hip_runtime.h>
#include <hip/hip_bf16.h>
#include <math.h>

#define B_    8
#define T_    2560
#define F_    229
#define C1_   5
#define C2_   11
#define W1_   114   // after first pool
#define W2_   57    // after second pool
#define KP_   640   // padded feature dim (627 -> 640) for MFMA
#define OF_   88
#define MC_   48
#define G_    8
#define DH_   6
#define K_    31
#define PAD_  15
#define BN_EPS 1e-5f
#define LN_EPS 1e-5f

typedef __attribute__((ext_vector_type(8))) short short8;
typedef __attribute__((ext_vector_type(4))) float f32x4;

static inline int cdiv(int a, int b) { return (a + b - 1) / b; }

// ---------------- conv1: 1 -> 5, 3x3 SAME, + bn + relu ----------------
__global__ __launch_bounds__(256) void conv1_kernel(const float* __restrict__ spec,
        const float* __restrict__ w, const float* __restrict__ cb,
        const float* __restrict__ g, const float* __restrict__ bb,
        const float* __restrict__ m, const float* __restrict__ vv,
        float* __restrict__ out) {
    int idx = blockIdx.x * 256 + threadIdx.x;
    if (idx >= B_ * T_ * F_) return;
    int f = idx % F_;
    int t = (idx / F_) % T_;
    int b = idx / (F_ * T_);
    const float* sp = spec + (size_t)b * T_ * F_;
    float tap[3][3];
#pragma unroll
    for (int dt = 0; dt < 3; ++dt) {
        int tt = t + dt - 1;
        bool tv = (tt >= 0 && tt < T_);
#pragma unroll
        for (int df = 0; df < 3; ++df) {
            int ff = f + df - 1;
            tap[dt][df] = (tv && ff >= 0 && ff < F_) ? sp[(size_t)tt * F_ + ff] : 0.f;
        }
    }
#pragma unroll
    for (int co = 0; co < C1_; ++co) {
        float acc = 0.f;
#pragma unroll
        for (int k = 0; k < 9; ++k) acc += tap[k / 3][k % 3] * w[co * 9 + k];
        float scl = g[co] * rsqrtf(vv[co] + BN_EPS);
        float y = (acc + cb[co] - m[co]) * scl + bb[co];
        out[((size_t)(b * C1_ + co) * T_ + t) * F_ + f] = fmaxf(y, 0.f);
    }
}

// ------- conv2 (5->5, 3x3 SAME) + bn + relu + maxpool w2, LDS-tiled -------
template <int CIN, int COUT, int WIN, int WLDS, int NTHR>
__global__ __launch_bounds__(NTHR) void conv_pool_kernel(const float* __restrict__ in,
        const float* __restrict__ w, const float* __restrict__ cb,
        const float* __restrict__ g, const float* __restrict__ bb,
        const float* __restrict__ m, const float* __restrict__ vv,
        float* __restrict__ out) {
    const int WOUT = WIN / 2;
    __shared__ float tile[4 * CIN * WLDS];
    __shared__ float wl[CIN * 3 * COUT * 4];
    __shared__ float scl_s[COUT], shf_s[COUT];
    int t0 = blockIdx.x * 2;
    int b = blockIdx.y;
    int tid = threadIdx.x;
    for (int i = tid; i < 4 * CIN * WLDS; i += NTHR) {
        int wc = i % WLDS;
        int ci = (i / WLDS) % CIN;
        int rr = i / (WLDS * CIN);
        int r = t0 - 1 + rr;
        int f = wc - 1;
        float v = 0.f;
        if (r >= 0 && r < T_ && f >= 0 && f < WIN)
            v = in[((size_t)(b * CIN + ci) * T_ + r) * WIN + f];
        tile[i] = v;
    }
    for (int i = tid; i < CIN * 3 * COUT * 4; i += NTHR) {
        int dw = i & 3;
        int co = (i >> 2) % COUT;
        int dt = (i / (4 * COUT)) % 3;
        int ci = i / (12 * COUT);
        wl[i] = (dw < 3) ? w[(co * CIN + ci) * 9 + dt * 3 + dw] : 0.f;
    }
    if (tid < COUT) {
        float s = g[tid] * rsqrtf(vv[tid] + BN_EPS);
        scl_s[tid] = s;
        shf_s[tid] = (cb[tid] - m[tid]) * s + bb[tid];
    }
    __syncthreads();
    int j = tid;
    if (j >= WOUT) return;
    float a0[2][COUT], a1[2][COUT];
#pragma unroll
    for (int tt = 0; tt < 2; ++tt)
#pragma unroll
        for (int co = 0; co < COUT; ++co) { a0[tt][co] = 0.f; a1[tt][co] = 0.f; }
#pragma unroll
    for (int ci = 0; ci < CIN; ++ci) {
        float tp4[4][4];
#pragma unroll
        for (int rr = 0; rr < 4; ++rr) {
            const float* p = &tile[(rr * CIN + ci) * WLDS + 2 * j];
            float2 x0 = *(const float2*)p;
            float2 x1 = *(const float2*)(p + 2);
            tp4[rr][0] = x0.x; tp4[rr][1] = x0.y; tp4[rr][2] = x1.x; tp4[rr][3] = x1.y;
        }
#pragma unroll
        for (int dt = 0; dt < 3; ++dt) {
#pragma unroll
            for (int co = 0; co < COUT; ++co) {
                const float4 wv = *(const float4*)&wl[((ci * 3 + dt) * COUT + co) * 4];
#pragma unroll
                for (int tt = 0; tt < 2; ++tt) {
                    int rr = dt + tt;
                    a0[tt][co] += tp4[rr][0] * wv.x + tp4[rr][1] * wv.y + tp4[rr][2] * wv.z;
                    a1[tt][co] += tp4[rr][1] * wv.x + tp4[rr][2] * wv.y + tp4[rr][3] * wv.z;
                }
            }
        }
    }
#pragma unroll
    for (int co = 0; co < COUT; ++co) {
        float s = scl_s[co], sh = shf_s[co];
#pragma unroll
        for (int tt = 0; tt < 2; ++tt) {
            float y0 = fmaxf(a0[tt][co] * s + sh, 0.f);
            float y1 = fmaxf(a1[tt][co] * s + sh, 0.f);
            out[((size_t)(b * COUT + co) * T_ + t0 + tt) * WOUT + j] = fmaxf(y0, y1);
        }
    }
}

// ------- conv3 (5->11) + bn + relu + pool, writes bf16 [bt][640] layout -------
__global__ __launch_bounds__(64) void conv3_pool_kernel(const float* __restrict__ in,
        const float* __restrict__ w, const float* __restrict__ cb,
        const float* __restrict__ g, const float* __restrict__ bb,
        const float* __restrict__ m, const float* __restrict__ vv,
        __hip_bfloat16* __restrict__ out) {
    const int CIN = 5, COUT = 11, WIN = 114, WLDS = 120, NTHR = 64, WOUT = 57;
    __shared__ float tile[4 * CIN * WLDS];
    __shared__ float wl[CIN * 3 * COUT * 4];
    __shared__ float scl_s[COUT], shf_s[COUT];
    int t0 = blockIdx.x * 2;
    int b = blockIdx.y;
    int tid = threadIdx.x;
    for (int i = tid; i < 4 * CIN * WLDS; i += NTHR) {
        int wc = i % WLDS;
        int ci = (i / WLDS) % CIN;
        int rr = i / (WLDS * CIN);
        int r = t0 - 1 + rr;
        int f = wc - 1;
        float v = 0.f;
        if (r >= 0 && r < T_ && f >= 0 && f < WIN)
            v = in[((size_t)(b * CIN + ci) * T_ + r) * WIN + f];
        tile[i] = v;
    }
    for (int i = tid; i < CIN * 3 * COUT * 4; i += NTHR) {
        int dw = i & 3;
        int co = (i >> 2) % COUT;
        int dt = (i / (4 * COUT)) % 3;
        int ci = i / (12 * COUT);
        wl[i] = (dw < 3) ? w[(co * CIN + ci) * 9 + dt * 3 + dw] : 0.f;
    }
    if (tid < COUT) {
        float s = g[tid] * rsqrtf(vv[tid] + BN_EPS);
        scl_s[tid] = s;
        shf_s[tid] = (cb[tid] - m[tid]) * s + bb[tid];
    }
    __syncthreads();
    int j = tid;
    if (j >= WOUT) return;
    float a0[2][COUT], a1[2][COUT];
#pragma unroll
    for (int tt = 0; tt < 2; ++tt)
#pragma unroll
        for (int co = 0; co < COUT; ++co) { a0[tt][co] = 0.f; a1[tt][co] = 0.f; }
#pragma unroll
    for (int ci = 0; ci < CIN; ++ci) {
        float tp4[4][4];
#pragma unroll
        for (int rr = 0; rr < 4; ++rr) {
            const float* p = &tile[(rr * CIN + ci) * WLDS + 2 * j];
            float2 x0 = *(const float2*)p;
            float2 x1 = *(const float2*)(p + 2);
            tp4[rr][0] = x0.x; tp4[rr][1] = x0.y; tp4[rr][2] = x1.x; tp4[rr][3] = x1.y;
        }
#pragma unroll
        for (int dt = 0; dt < 3; ++dt) {
#pragma unroll
            for (int co = 0; co < COUT; ++co) {
                const float4 wv = *(const float4*)&wl[((ci * 3 + dt) * COUT + co) * 4];
#pragma unroll
                for (int tt = 0; tt < 2; ++tt) {
                    int rr = dt + tt;
                    a0[tt][co] += tp4[rr][0] * wv.x + tp4[rr][1] * wv.y + tp4[rr][2] * wv.z;
                    a1[tt][co] += tp4[rr][1] * wv.x + tp4[rr][2] * wv.y + tp4[rr][3] * wv.z;
                }
            }
        }
    }
    size_t row0 = (size_t)(b * T_ + t0) * KP_;
    size_t row1 = (size_t)(b * T_ + t0 + 1) * KP_;
#pragma unroll
    for (int co = 0; co < COUT; ++co) {
        float s = scl_s[co], sh = shf_s[co];
        float y00 = fmaxf(a0[0][co] * s + sh, 0.f);
        float y10 = fmaxf(a1[0][co] * s + sh, 0.f);
        float y01 = fmaxf(a0[1][co] * s + sh, 0.f);
        float y11 = fmaxf(a1[1][co] * s + sh, 0.f);
        out[row0 + co * 57 + j] = __float2bfloat16(fmaxf(y00, y10));
        out[row1 + co * 57 + j] = __float2bfloat16(fmaxf(y01, y11));
    }
    // zero the K padding (627..639) for both rows
    if (j < KP_ - 627) {
        out[row0 + 627 + j] = __float2bfloat16(0.f);
        out[row1 + 627 + j] = __float2bfloat16(0.f);
    }
}

// -------- W' = [wq;wk;wv] @ fc_w -> bf16 [144][640] (padded), b' fp32 --------
__global__ __launch_bounds__(256) void wprime_kernel(const float* __restrict__ fc_w,
        const float* __restrict__ fc_b, const float* __restrict__ wq,
        const float* __restrict__ wk, const float* __restrict__ wv,
        __hip_bfloat16* __restrict__ wp, float* __restrict__ bp) {
    int idx = blockIdx.x * 256 + threadIdx.x;
    if (idx < 144 * KP_) {
        int o = idx / KP_;
        int kk = idx % KP_;
        const float* Wrow = (o < 48) ? (wq + o * 88)
                          : (o < 96) ? (wk + (o - 48) * 88) : (wv + (o - 96) * 88);
        float s = 0.f;
        if (kk < 627)
            for (int i = 0; i < 88; ++i) s += Wrow[i] * fc_w[(size_t)i * 627 + kk];
        wp[idx] = __float2bfloat16(s);
    } else if (idx < 144 * KP_ + 144) {
        int o = idx - 144 * KP_;
        const float* Wrow = (o < 48) ? (wq + o * 88)
                          : (o < 96) ? (wk + (o - 48) * 88) : (wv + (o - 96) * 88);
        float s = 0.f;
        for (int i = 0; i < 88; ++i) s += Wrow[i] * fc_b[i];
        bp[o] = s;
    }
}

// -------- fused FC+QKV via MFMA bf16: Q[bt][144] = X[bt][640] @ W'^T + b' --------
// 4 waves/block, each wave independent: 16 rows x 48 cols, K=640 (20 steps).
// No LDS, no barriers; A/B fragments loaded as 16B dwordx4 from global.
__global__ __launch_bounds__(256) void fc_qkv_mfma_kernel(
        const __hip_bfloat16* __restrict__ X, const __hip_bfloat16* __restrict__ Wp,
        const float* __restrict__ bp, float* __restrict__ Q) {
    int tid = threadIdx.x;
    int lane = tid & 63;
    int gw = blockIdx.x * 4 + (tid >> 6);      // 0..3839
    int mtile = gw / 3;                        // 0..1279
    int nthird = gw % 3;                       // 0..2
    const short* Xs = (const short*)X;
    const short* Ws = (const short*)Wp;
    int klane = (lane >> 4) * 8;               // k sub-offset within 32-chunk
    const short* xrow = Xs + (size_t)(mtile * 16 + (lane & 15)) * KP_ + klane;
    const short* wrow = Ws + (size_t)(nthird * 48 + (lane & 15)) * KP_ + klane;
    f32x4 acc0 = {0.f, 0.f, 0.f, 0.f}, acc1 = acc0, acc2 = acc0;
#pragma unroll 4
    for (int kt = 0; kt < 20; ++kt) {
        short8 a = *(const short8*)(xrow + kt * 32);
        short8 b0 = *(const short8*)(wrow + kt * 32);
        short8 b1 = *(const short8*)(wrow + 16 * KP_ + kt * 32);
        short8 b2 = *(const short8*)(wrow + 32 * KP_ + kt * 32);
        acc0 = __builtin_amdgcn_mfma_f32_16x16x32_bf16(a, b0, acc0, 0, 0, 0);
        acc1 = __builtin_amdgcn_mfma_f32_16x16x32_bf16(a, b1, acc1, 0, 0, 0);
        acc2 = __builtin_amdgcn_mfma_f32_16x16x32_bf16(a, b2, acc2, 0, 0, 0);
    }
    // C/D layout: col = lane&15, row = (lane>>4)*4 + reg
    int r0 = mtile * 16 + (lane >> 4) * 4;
    int col = lane & 15;
    f32x4 accs[3] = {acc0, acc1, acc2};
#pragma unroll
    for (int nt = 0; nt < 3; ++nt) {
        int o = nthird * 48 + nt * 16 + col;
        float bias = bp[o];
#pragma unroll
        for (int rg = 0; rg < 4; ++rg)
            Q[(size_t)(r0 + rg) * 144 + o] = accs[nt][rg] + bias;
    }
}

// ---------------- windowed relative attention, LDS-tiled ----------------
__global__ __launch_bounds__(256) void attn_kernel(const float* __restrict__ Q,
        const float* __restrict__ rel, float* __restrict__ attout,
        float* __restrict__ aout) {
    __shared__ float kv[94 * 144];
    __shared__ float relT[31 * 48];
    int b = blockIdx.y;
    int t0 = blockIdx.x * 64;
    int tid = threadIdx.x;
    for (int i = tid; i < 94 * 144; i += 256) {
        int rr = i / 144, c = i % 144;
        int r = t0 - 15 + rr;
        kv[i] = (r >= 0 && r < T_) ? Q[((size_t)b * T_ + r) * 144 + c] : 0.f;
    }
    for (int i = tid; i < 31 * 48; i += 256) {
        int kp = i / 48, jj = i % 48;
        relT[i] = rel[jj * 31 + kp];
    }
    __syncthreads();
    for (int it = tid; it < 512; it += 256) {
        int g = it & 7;
        int tl = it >> 3;
        const float* qp = &kv[(tl + 15) * 144 + g * 6];
        float q0 = qp[0], q1 = qp[1], q2 = qp[2], q3 = qp[3], q4 = qp[4], q5 = qp[5];
        float e[31];
        float emax = -1e30f;
#pragma unroll
        for (int kp = 0; kp < 31; ++kp) {
            const float* kr = &kv[(tl + kp) * 144 + 48 + g * 6];
            const float* rr = &relT[kp * 48 + g * 6];
            float s = q0 * (kr[0] + rr[0]) + q1 * (kr[1] + rr[1]) + q2 * (kr[2] + rr[2]) +
                      q3 * (kr[3] + rr[3]) + q4 * (kr[4] + rr[4]) + q5 * (kr[5] + rr[5]);
            e[kp] = s;
            emax = fmaxf(emax, s);
        }
        float sum = 0.f;
#pragma unroll
        for (int kp = 0; kp < 31; ++kp) { e[kp] = __expf(e[kp] - emax); sum += e[kp]; }
        float inv = 1.f / sum;
        float o0 = 0, o1 = 0, o2 = 0, o3 = 0, o4 = 0, o5 = 0;
        int t = t0 + tl;
        float* ap = &aout[(((size_t)b * T_ + t) * 8 + g) * 31];
#pragma unroll
        for (int kp = 0; kp < 31; ++kp) {
            float a = e[kp] * inv;
            ap[kp] = a;
            const float* vr = &kv[(tl + kp) * 144 + 96 + g * 6];
            o0 += a * vr[0]; o1 += a * vr[1]; o2 += a * vr[2];
            o3 += a * vr[3]; o4 += a * vr[4]; o5 += a * vr[5];
        }
        float* op = &attout[((size_t)b * T_ + t) * 48 + g * 6];
        op[0] = o0; op[1] = o1; op[2] = o2; op[3] = o3; op[4] = o4; op[5] = o5;
    }
}

// ---------- LayerNorm(48) + linear(48->88) + sigmoid, 32 rows/block ----------
__global__ __launch_bounds__(256) void ln_kernel(const float* __restrict__ att,
        const float* __restrict__ lng, const float* __restrict__ lnb,
        const float* __restrict__ lw, const float* __restrict__ lb,
        float* __restrict__ fp) {
    __shared__ float xr[32 * 48];
    __shared__ float wl[88 * 48];
    __shared__ float mus[32], rss[32], gs[48], bs[48], lbs[88];
    int row0 = blockIdx.x * 32;
    int tid = threadIdx.x;
    for (int i = tid; i < 32 * 48; i += 256) xr[i] = att[(size_t)row0 * 48 + i];
    for (int i = tid; i < 88 * 48; i += 256) wl[i] = lw[i];
    if (tid < 48) { gs[tid] = lng[tid]; bs[tid] = lnb[tid]; }
    if (tid < 88) lbs[tid] = lb[tid];
    __syncthreads();
    if (tid < 32) {
        float s = 0.f;
        for (int c = 0; c < 48; ++c) s += xr[tid * 48 + c];
        float mu = s * (1.f / 48.f);
        float v2 = 0.f;
        for (int c = 0; c < 48; ++c) { float d = xr[tid * 48 + c] - mu; v2 += d * d; }
        mus[tid] = mu;
        rss[tid] = rsqrtf(v2 * (1.f / 48.f) + LN_EPS);
    }
    __syncthreads();
    for (int i = tid; i < 32 * 48; i += 256) {
        int r = i / 48, c = i % 48;
        xr[i] = (xr[i] - mus[r]) * rss[r] * gs[c] + bs[c];
    }
    __syncthreads();
    for (int k = 0; k < 11; ++k) {
        int cid = k * 256 + tid;
        int o = cid % 88, r = cid / 88;
        const float* xp = &xr[r * 48];
        const float* wpp = &wl[o * 48];
        float s = lbs[o];
#pragma unroll
        for (int c = 0; c < 48; c += 4) {
            float4 xv = *(const float4*)&xp[c];
            float4 wv = *(const float4*)&wpp[c];
            s += xv.x * wv.x + xv.y * wv.y + xv.z * wv.z + xv.w * wv.w;
        }
        fp[(size_t)row0 * 88 + cid] = 1.f / (1.f + __expf(-s));
    }
}

extern "C" void kernel_launch(void* const* d_in, const int* in_sizes, int n_in,
                              void* d_out, int out_size, void* d_ws, size_t ws_size,
                              hipStream_t stream) {
    const float* spec = (const float*)d_in[0];
    const float* c1_w = (const float*)d_in[1];
    const float* c1_b = (const float*)d_in[2];
    const float* bn1_g = (const float*)d_in[3];
    const float* bn1_b = (const float*)d_in[4];
    const float* bn1_m = (const float*)d_in[5];
    const float* bn1_v = (const float*)d_in[6];
    const float* c2_w = (const float*)d_in[7];
    const float* c2_b = (const float*)d_in[8];
    const float* bn2_g = (const float*)d_in[9];
    const float* bn2_b = (const float*)d_in[10];
    const float* bn2_m = (const float*)d_in[11];
    const float* bn2_v = (const float*)d_in[12];
    const float* c3_w = (const float*)d_in[13];
    const float* c3_b = (const float*)d_in[14];
    const float* bn3_g = (const float*)d_in[15];
    const float* bn3_b = (const float*)d_in[16];
    const float* bn3_m = (const float*)d_in[17];
    const float* bn3_v = (const float*)d_in[18];
    const float* fc_w = (const float*)d_in[19];
    const float* fc_b = (const float*)d_in[20];
    const float* wq = (const float*)d_in[21];
    const float* wk = (const float*)d_in[22];
    const float* wv = (const float*)d_in[23];
    const float* rel = (const float*)d_in[24];
    const float* ln_g = (const float*)d_in[25];
    const float* ln_b = (const float*)d_in[26];
    const float* lin_w = (const float*)d_in[27];
    const float* lin_b = (const float*)d_in[28];

    // workspace layout (floats):
    // region A [0, 23449600): x1 (fp32); later x3bf (bf16, 13.1M floats) -- no overlap issue
    //   wp_bf at +14000000 (bf16 144*640 = 46,080 floats), bp at +14200000
    // region B [23449600, ...): x2p (fp32 11.67M); later Qb fp32 + attout
    const size_t X1_ELEMS = (size_t)B_ * C1_ * T_ * F_;  // 23,449,600
    float* ws = (float*)d_ws;
    float* x1 = ws;
    __hip_bfloat16* x3bf = (__hip_bfloat16*)ws;           // 20480*640 bf16 = 26.2 MB
    __hip_bfloat16* wp_bf = (__hip_bfloat16*)(ws + 14000000);
    float* bp = ws + 14200000;
    float* regB = ws + X1_ELEMS;
    float* x2p = regB;
    float* Qb = regB;                   // 20480*144 fp32 (x2p dead by then)
    float* attout = regB + 3000000;

    float* frame_pred = (float*)d_out;
    float* a_out = frame_pred + (size_t)B_ * T_ * OF_;

    // 1. conv1 + bn + relu -> x1 (B,5,T,229)
    conv1_kernel<<<cdiv(B_ * T_ * F_, 256), 256, 0, stream>>>(spec, c1_w, c1_b, bn1_g,
                                                              bn1_b, bn1_m, bn1_v, x1);
    // 2. conv2 + bn + relu + pool -> x2p (B,5,T,114)
    conv_pool_kernel<C1_, C1_, F_, 232, 128><<<dim3(T_ / 2, B_), 128, 0, stream>>>(
        x1, c2_w, c2_b, bn2_g, bn2_b, bn2_m, bn2_v, x2p);
    // 3. W' bf16 [144][640] + b' (x1 region reused after conv2)
    wprime_kernel<<<cdiv(144 * KP_ + 144, 256), 256, 0, stream>>>(fc_w, fc_b, wq, wk, wv,
                                                                  wp_bf, bp);
    // 4. conv3 + bn + relu + pool -> x3bf (bf16 [bt][640], zero-padded)
    conv3_pool_kernel<<<dim3(T_ / 2, B_), 64, 0, stream>>>(x2p, c3_w, c3_b, bn3_g, bn3_b,
                                                           bn3_m, bn3_v, x3bf);
    // 5. fused FC+QKV MFMA -> Qb (B*T,144) fp32
    fc_qkv_mfma_kernel<<<960, 256, 0, stream>>>(x3bf, wp_bf, bp, Qb);
    // 6. attention -> attout (B*T,48), a_out (B,T,8,31)
    attn_kernel<<<dim3(T_ / 64, B_), 256, 0, stream>>>(Qb, rel, attout, a_out);
    // 7. LN + linear + sigmoid -> frame_pred (B,T,88)
    ln_kernel<<<(B_ * T_) / 32, 256, 0, stream>>>(attout, ln_g, ln_b, lin_w, lin_b,
                                                  frame_pred);
}

// Round 5
// 437.976 us; speedup vs baseline: 4.3655x; 1.0913x over previous
//
#include <hip/hip_runtime.h>
#include <hip/hip_bf16.h>
#include <math.h>

#define B_    8
#define T_    2560
#define F_    229
#define C1_   5
#define C2_   11
#define W1_   114   // after first pool
#define W2_   57    // after second pool
#define KP_   640   // padded feature dim (627 -> 640) for MFMA
#define OF_   88
#define MC_   48
#define G_    8
#define DH_   6
#define K_    31
#define PAD_  15
#define BN_EPS 1e-5f
#define LN_EPS 1e-5f
#define TS_   8     // t-rows per fused conv block

typedef __attribute__((ext_vector_type(8))) short short8;
typedef __attribute__((ext_vector_type(4))) float f32x4;

static inline int cdiv(int a, int b) { return (a + b - 1) / b; }

__device__ inline float bfbits_lo(unsigned u) { return __uint_as_float(u << 16); }
__device__ inline float bfbits_hi(unsigned u) { return __uint_as_float(u & 0xffff0000u); }

// ---------------- conv1: 1 -> 5, 3x3 SAME, + bn + relu -> bf16 ----------------
__global__ __launch_bounds__(256) void conv1_kernel(const float* __restrict__ spec,
        const float* __restrict__ w, const float* __restrict__ cb,
        const float* __restrict__ g, const float* __restrict__ bb,
        const float* __restrict__ m, const float* __restrict__ vv,
        __hip_bfloat16* __restrict__ out) {
    int idx = blockIdx.x * 256 + threadIdx.x;
    if (idx >= B_ * T_ * F_) return;
    int f = idx % F_;
    int t = (idx / F_) % T_;
    int b = idx / (F_ * T_);
    const float* sp = spec + (size_t)b * T_ * F_;
    float tap[3][3];
#pragma unroll
    for (int dt = 0; dt < 3; ++dt) {
        int tt = t + dt - 1;
        bool tv = (tt >= 0 && tt < T_);
#pragma unroll
        for (int df = 0; df < 3; ++df) {
            int ff = f + df - 1;
            tap[dt][df] = (tv && ff >= 0 && ff < F_) ? sp[(size_t)tt * F_ + ff] : 0.f;
        }
    }
#pragma unroll
    for (int co = 0; co < C1_; ++co) {
        float acc = 0.f;
#pragma unroll
        for (int k = 0; k < 9; ++k) acc += tap[k / 3][k % 3] * w[co * 9 + k];
        float scl = g[co] * rsqrtf(vv[co] + BN_EPS);
        float y = (acc + cb[co] - m[co]) * scl + bb[co];
        out[((size_t)(b * C1_ + co) * T_ + t) * F_ + f] = __float2bfloat16(fmaxf(y, 0.f));
    }
}

// ------- fused conv2+pool+conv3+pool: x1bf (B,5,T,229) -> x3bf [bt][640] -------
// block = (b, 8-t slab), 640 threads. x1 tile fp32 in LDS (12 rows), x2p tile
// bf16 in LDS (10 rows, never hits HBM), conv3 writes bf16 MFMA layout.
__global__ __launch_bounds__(640, 5) void conv23_kernel(
        const __hip_bfloat16* __restrict__ x1bf,
        const float* __restrict__ c2w, const float* __restrict__ c2b,
        const float* __restrict__ g2, const float* __restrict__ b2,
        const float* __restrict__ m2, const float* __restrict__ v2,
        const float* __restrict__ c3w, const float* __restrict__ c3b,
        const float* __restrict__ g3, const float* __restrict__ b3,
        const float* __restrict__ m3, const float* __restrict__ v3,
        __hip_bfloat16* __restrict__ x3out) {
    __shared__ float x1t[12 * 5 * 232];          // 55,680 B  (col = f+1)
    __shared__ ushort x2pt[10 * 5 * 120];        // 12,000 B  (col = w+1)
    __shared__ float w2s[5 * 5 * 9], w3s[11 * 5 * 9];
    __shared__ float scl2[5], shf2[5], scl3[11], shf3[11];
    int t0 = blockIdx.x * TS_;
    int b = blockIdx.y;
    int tid = threadIdx.x;

    for (int i = tid; i < 225; i += 640) w2s[i] = c2w[i];
    for (int i = tid; i < 495; i += 640) w3s[i] = c3w[i];
    if (tid < 5) {
        float s = g2[tid] * rsqrtf(v2[tid] + BN_EPS);
        scl2[tid] = s;
        shf2[tid] = (c2b[tid] - m2[tid]) * s + b2[tid];
    }
    if (tid >= 64 && tid < 75) {
        int c = tid - 64;
        float s = g3[c] * rsqrtf(v3[c] + BN_EPS);
        scl3[c] = s;
        shf3[c] = (c3b[c] - m3[c]) * s + b3[c];
    }
    // stage x1 rows t0-2 .. t0+9 (fp32, zero-padded)
    const ushort* x1u = (const ushort*)x1bf;
    for (int i = tid; i < 12 * 5 * 232; i += 640) {
        int col = i % 232;
        int ci = (i / 232) % 5;
        int rr = i / 1160;
        int t = t0 - 2 + rr;
        int f = col - 1;
        float v = 0.f;
        if (t >= 0 && t < T_ && f >= 0 && f < F_)
            v = bfbits_lo(x1u[((size_t)(b * 5 + ci) * T_ + t) * F_ + f]);
        x1t[i] = v;
    }
    __syncthreads();

    // ---- phase 2: conv2+bn+relu+pool -> x2pt rows t0-1..t0+8 ----
    if (tid < 570) {
        int co = tid / 114;
        int j = tid % 114;
        float acc0[10], acc1[10];
#pragma unroll
        for (int r = 0; r < 10; ++r) { acc0[r] = 0.f; acc1[r] = 0.f; }
#pragma unroll
        for (int ci = 0; ci < 5; ++ci) {
            float wr[9];
#pragma unroll
            for (int k = 0; k < 9; ++k) wr[k] = w2s[(co * 5 + ci) * 9 + k];
#pragma unroll
            for (int rr = 0; rr < 12; ++rr) {
                const float* p = &x1t[(rr * 5 + ci) * 232 + 2 * j];
                float2 a = *(const float2*)p;
                float2 bq = *(const float2*)(p + 2);
                float v0 = a.x, v1 = a.y, v2_ = bq.x, v3_ = bq.y;
#pragma unroll
                for (int dt = 0; dt < 3; ++dt) {
                    int r = rr - dt;
                    if (r >= 0 && r < 10) {
                        acc0[r] += v0 * wr[dt * 3] + v1 * wr[dt * 3 + 1] + v2_ * wr[dt * 3 + 2];
                        acc1[r] += v1 * wr[dt * 3] + v2_ * wr[dt * 3 + 1] + v3_ * wr[dt * 3 + 2];
                    }
                }
            }
        }
        float s = scl2[co], sh = shf2[co];
#pragma unroll
        for (int r = 0; r < 10; ++r) {
            int t = t0 - 1 + r;
            float y0 = fmaxf(acc0[r] * s + sh, 0.f);
            float y1 = fmaxf(acc1[r] * s + sh, 0.f);
            float y = fmaxf(y0, y1);
            if (t < 0 || t >= T_) y = 0.f;
            __hip_bfloat16 h = __float2bfloat16(y);
            x2pt[(r * 5 + co) * 120 + 1 + j] = *(ushort*)&h;
        }
    } else {
        // zero padding cols 0, 115..119 of x2pt
        for (int i = tid - 570; i < 300; i += 70) {
            int cc = i % 6;
            int col = (cc == 0) ? 0 : 114 + cc;
            int ci = (i / 6) % 5;
            int r = i / 30;
            x2pt[(r * 5 + ci) * 120 + col] = 0;
        }
    }
    __syncthreads();

    // ---- phase 3: conv3+bn+relu+pool -> x3out bf16 [bt][640] ----
    if (tid < 627) {
        int co = tid / 57;
        int j = tid % 57;
        float acc0[8], acc1[8];
#pragma unroll
        for (int r = 0; r < 8; ++r) { acc0[r] = 0.f; acc1[r] = 0.f; }
#pragma unroll
        for (int ci = 0; ci < 5; ++ci) {
            float wr[9];
#pragma unroll
            for (int k = 0; k < 9; ++k) wr[k] = w3s[(co * 5 + ci) * 9 + k];
#pragma unroll
            for (int rr = 0; rr < 10; ++rr) {
                const ushort* p = &x2pt[(rr * 5 + ci) * 120 + 2 * j];
                unsigned u0 = *(const unsigned*)p;
                unsigned u1 = *(const unsigned*)(p + 2);
                float v0 = bfbits_lo(u0), v1 = bfbits_hi(u0);
                float v2_ = bfbits_lo(u1), v3_ = bfbits_hi(u1);
#pragma unroll
                for (int dt = 0; dt < 3; ++dt) {
                    int r = rr - dt;
                    if (r >= 0 && r < 8) {
                        acc0[r] += v0 * wr[dt * 3] + v1 * wr[dt * 3 + 1] + v2_ * wr[dt * 3 + 2];
                        acc1[r] += v1 * wr[dt * 3] + v2_ * wr[dt * 3 + 1] + v3_ * wr[dt * 3 + 2];
                    }
                }
            }
        }
        float s = scl3[co], sh = shf3[co];
#pragma unroll
        for (int r = 0; r < 8; ++r) {
            float y0 = fmaxf(acc0[r] * s + sh, 0.f);
            float y1 = fmaxf(acc1[r] * s + sh, 0.f);
            x3out[(size_t)(b * T_ + t0 + r) * KP_ + co * 57 + j] =
                __float2bfloat16(fmaxf(y0, y1));
        }
    } else {
        // tid 627..639: zero K-padding cols 627..639
        __hip_bfloat16 z = __float2bfloat16(0.f);
#pragma unroll
        for (int r = 0; r < 8; ++r)
            x3out[(size_t)(b * T_ + t0 + r) * KP_ + tid] = z;
    }
}

// -------- W' = [wq;wk;wv] @ fc_w -> bf16 [144][640] (padded), b' fp32 --------
__global__ __launch_bounds__(256) void wprime_kernel(const float* __restrict__ fc_w,
        const float* __restrict__ fc_b, const float* __restrict__ wq,
        const float* __restrict__ wk, const float* __restrict__ wv,
        __hip_bfloat16* __restrict__ wp, float* __restrict__ bp) {
    int idx = blockIdx.x * 256 + threadIdx.x;
    if (idx < 144 * KP_) {
        int o = idx / KP_;
        int kk = idx % KP_;
        const float* Wrow = (o < 48) ? (wq + o * 88)
                          : (o < 96) ? (wk + (o - 48) * 88) : (wv + (o - 96) * 88);
        float s = 0.f;
        if (kk < 627)
            for (int i = 0; i < 88; ++i) s += Wrow[i] * fc_w[(size_t)i * 627 + kk];
        wp[idx] = __float2bfloat16(s);
    } else if (idx < 144 * KP_ + 144) {
        int o = idx - 144 * KP_;
        const float* Wrow = (o < 48) ? (wq + o * 88)
                          : (o < 96) ? (wk + (o - 48) * 88) : (wv + (o - 96) * 88);
        float s = 0.f;
        for (int i = 0; i < 88; ++i) s += Wrow[i] * fc_b[i];
        bp[o] = s;
    }
}

// -------- fused FC+QKV via MFMA bf16: Q[bt][144] = X[bt][640] @ W'^T + b' --------
__global__ __launch_bounds__(256) void fc_qkv_mfma_kernel(
        const __hip_bfloat16* __restrict__ X, const __hip_bfloat16* __restrict__ Wp,
        const float* __restrict__ bp, float* __restrict__ Q) {
    int tid = threadIdx.x;
    int lane = tid & 63;
    int gw = blockIdx.x * 4 + (tid >> 6);      // 0..3839
    int mtile = gw / 3;                        // 0..1279
    int nthird = gw % 3;                       // 0..2
    const short* Xs = (const short*)X;
    const short* Ws = (const short*)Wp;
    int klane = (lane >> 4) * 8;
    const short* xrow = Xs + (size_t)(mtile * 16 + (lane & 15)) * KP_ + klane;
    const short* wrow = Ws + (size_t)(nthird * 48 + (lane & 15)) * KP_ + klane;
    f32x4 acc0 = {0.f, 0.f, 0.f, 0.f}, acc1 = acc0, acc2 = acc0;
#pragma unroll 4
    for (int kt = 0; kt < 20; ++kt) {
        short8 a = *(const short8*)(xrow + kt * 32);
        short8 b0 = *(const short8*)(wrow + kt * 32);
        short8 b1 = *(const short8*)(wrow + 16 * KP_ + kt * 32);
        short8 b2 = *(const short8*)(wrow + 32 * KP_ + kt * 32);
        acc0 = __builtin_amdgcn_mfma_f32_16x16x32_bf16(a, b0, acc0, 0, 0, 0);
        acc1 = __builtin_amdgcn_mfma_f32_16x16x32_bf16(a, b1, acc1, 0, 0, 0);
        acc2 = __builtin_amdgcn_mfma_f32_16x16x32_bf16(a, b2, acc2, 0, 0, 0);
    }
    int r0 = mtile * 16 + (lane >> 4) * 4;
    int col = lane & 15;
    f32x4 accs[3] = {acc0, acc1, acc2};
#pragma unroll
    for (int nt = 0; nt < 3; ++nt) {
        int o = nthird * 48 + nt * 16 + col;
        float bias = bp[o];
#pragma unroll
        for (int rg = 0; rg < 4; ++rg)
            Q[(size_t)(r0 + rg) * 144 + o] = accs[nt][rg] + bias;
    }
}

// ---------------- windowed relative attention, LDS-tiled ----------------
__global__ __launch_bounds__(256) void attn_kernel(const float* __restrict__ Q,
        const float* __restrict__ rel, float* __restrict__ attout,
        float* __restrict__ aout) {
    __shared__ float kv[94 * 144];
    __shared__ float relT[31 * 48];
    int b = blockIdx.y;
    int t0 = blockIdx.x * 64;
    int tid = threadIdx.x;
    for (int i = tid; i < 94 * 144; i += 256) {
        int rr = i / 144, c = i % 144;
        int r = t0 - 15 + rr;
        kv[i] = (r >= 0 && r < T_) ? Q[((size_t)b * T_ + r) * 144 + c] : 0.f;
    }
    for (int i = tid; i < 31 * 48; i += 256) {
        int kp = i / 48, jj = i % 48;
        relT[i] = rel[jj * 31 + kp];
    }
    __syncthreads();
    for (int it = tid; it < 512; it += 256) {
        int g = it & 7;
        int tl = it >> 3;
        const float* qp = &kv[(tl + 15) * 144 + g * 6];
        float q0 = qp[0], q1 = qp[1], q2 = qp[2], q3 = qp[3], q4 = qp[4], q5 = qp[5];
        float e[31];
        float emax = -1e30f;
#pragma unroll
        for (int kp = 0; kp < 31; ++kp) {
            const float* kr = &kv[(tl + kp) * 144 + 48 + g * 6];
            const float* rr = &relT[kp * 48 + g * 6];
            float s = q0 * (kr[0] + rr[0]) + q1 * (kr[1] + rr[1]) + q2 * (kr[2] + rr[2]) +
                      q3 * (kr[3] + rr[3]) + q4 * (kr[4] + rr[4]) + q5 * (kr[5] + rr[5]);
            e[kp] = s;
            emax = fmaxf(emax, s);
        }
        float sum = 0.f;
#pragma unroll
        for (int kp = 0; kp < 31; ++kp) { e[kp] = __expf(e[kp] - emax); sum += e[kp]; }
        float inv = 1.f / sum;
        float o0 = 0, o1 = 0, o2 = 0, o3 = 0, o4 = 0, o5 = 0;
        int t = t0 + tl;
        float* ap = &aout[(((size_t)b * T_ + t) * 8 + g) * 31];
#pragma unroll
        for (int kp = 0; kp < 31; ++kp) {
            float a = e[kp] * inv;
            ap[kp] = a;
            const float* vr = &kv[(tl + kp) * 144 + 96 + g * 6];
            o0 += a * vr[0]; o1 += a * vr[1]; o2 += a * vr[2];
            o3 += a * vr[3]; o4 += a * vr[4]; o5 += a * vr[5];
        }
        float* op = &attout[((size_t)b * T_ + t) * 48 + g * 6];
        op[0] = o0; op[1] = o1; op[2] = o2; op[3] = o3; op[4] = o4; op[5] = o5;
    }
}

// ---------- LayerNorm(48) + linear(48->88) + sigmoid, 32 rows/block ----------
__global__ __launch_bounds__(256) void ln_kernel(const float* __restrict__ att,
        const float* __restrict__ lng, const float* __restrict__ lnb,
        const float* __restrict__ lw, const float* __restrict__ lb,
        float* __restrict__ fp) {
    __shared__ float xr[32 * 48];
    __shared__ float wl[88 * 48];
    __shared__ float mus[32], rss[32], gs[48], bs[48], lbs[88];
    int row0 = blockIdx.x * 32;
    int tid = threadIdx.x;
    for (int i = tid; i < 32 * 48; i += 256) xr[i] = att[(size_t)row0 * 48 + i];
    for (int i = tid; i < 88 * 48; i += 256) wl[i] = lw[i];
    if (tid < 48) { gs[tid] = lng[tid]; bs[tid] = lnb[tid]; }
    if (tid < 88) lbs[tid] = lb[tid];
    __syncthreads();
    if (tid < 32) {
        float s = 0.f;
        for (int c = 0; c < 48; ++c) s += xr[tid * 48 + c];
        float mu = s * (1.f / 48.f);
        float v2 = 0.f;
        for (int c = 0; c < 48; ++c) { float d = xr[tid * 48 + c] - mu; v2 += d * d; }
        mus[tid] = mu;
        rss[tid] = rsqrtf(v2 * (1.f / 48.f) + LN_EPS);
    }
    __syncthreads();
    for (int i = tid; i < 32 * 48; i += 256) {
        int r = i / 48, c = i % 48;
        xr[i] = (xr[i] - mus[r]) * rss[r] * gs[c] + bs[c];
    }
    __syncthreads();
    for (int k = 0; k < 11; ++k) {
        int cid = k * 256 + tid;
        int o = cid % 88, r = cid / 88;
        const float* xp = &xr[r * 48];
        const float* wpp = &wl[o * 48];
        float s = lbs[o];
#pragma unroll
        for (int c = 0; c < 48; c += 4) {
            float4 xv = *(const float4*)&xp[c];
            float4 wv = *(const float4*)&wpp[c];
            s += xv.x * wv.x + xv.y * wv.y + xv.z * wv.z + xv.w * wv.w;
        }
        fp[(size_t)row0 * 88 + cid] = 1.f / (1.f + __expf(-s));
    }
}

extern "C" void kernel_launch(void* const* d_in, const int* in_sizes, int n_in,
                              void* d_out, int out_size, void* d_ws, size_t ws_size,
                              hipStream_t stream) {
    const float* spec = (const float*)d_in[0];
    const float* c1_w = (const float*)d_in[1];
    const float* c1_b = (const float*)d_in[2];
    const float* bn1_g = (const float*)d_in[3];
    const float* bn1_b = (const float*)d_in[4];
    const float* bn1_m = (const float*)d_in[5];
    const float* bn1_v = (const float*)d_in[6];
    const float* c2_w = (const float*)d_in[7];
    const float* c2_b = (const float*)d_in[8];
    const float* bn2_g = (const float*)d_in[9];
    const float* bn2_b = (const float*)d_in[10];
    const float* bn2_m = (const float*)d_in[11];
    const float* bn2_v = (const float*)d_in[12];
    const float* c3_w = (const float*)d_in[13];
    const float* c3_b = (const float*)d_in[14];
    const float* bn3_g = (const float*)d_in[15];
    const float* bn3_b = (const float*)d_in[16];
    const float* bn3_m = (const float*)d_in[17];
    const float* bn3_v = (const float*)d_in[18];
    const float* fc_w = (const float*)d_in[19];
    const float* fc_b = (const float*)d_in[20];
    const float* wq = (const float*)d_in[21];
    const float* wk = (const float*)d_in[22];
    const float* wv = (const float*)d_in[23];
    const float* rel = (const float*)d_in[24];
    const float* ln_g = (const float*)d_in[25];
    const float* ln_b = (const float*)d_in[26];
    const float* lin_w = (const float*)d_in[27];
    const float* lin_b = (const float*)d_in[28];

    // workspace layout (float units):
    // [0, 6.6M): x3bf (bf16, 20480*640 = 13.1M bf16)
    // [7M, 18.73M): x1bf (bf16, 8*5*2560*229 = 23.45M bf16)
    // [19.0M, 19.1M): wp_bf (bf16 144*640); [19.1M,+144): bp
    // [23.45M, ...): Qb fp32 (2.95M); attout at +3M (983k)
    float* ws = (float*)d_ws;
    __hip_bfloat16* x3bf = (__hip_bfloat16*)ws;
    __hip_bfloat16* x1bf = (__hip_bfloat16*)(ws + 7000000);
    __hip_bfloat16* wp_bf = (__hip_bfloat16*)(ws + 19000000);
    float* bp = ws + 19100000;
    float* regB = ws + 23449600;
    float* Qb = regB;
    float* attout = regB + 3000000;

    float* frame_pred = (float*)d_out;
    float* a_out = frame_pred + (size_t)B_ * T_ * OF_;

    // 1. conv1 + bn + relu -> x1bf (B,5,T,229) bf16
    conv1_kernel<<<cdiv(B_ * T_ * F_, 256), 256, 0, stream>>>(spec, c1_w, c1_b, bn1_g,
                                                              bn1_b, bn1_m, bn1_v, x1bf);
    // 2. W' bf16 [144][640] + b'
    wprime_kernel<<<cdiv(144 * KP_ + 144, 256), 256, 0, stream>>>(fc_w, fc_b, wq, wk, wv,
                                                                  wp_bf, bp);
    // 3. fused conv2+pool+conv3+pool -> x3bf [bt][640]
    conv23_kernel<<<dim3(T_ / TS_, B_), 640, 0, stream>>>(
        x1bf, c2_w, c2_b, bn2_g, bn2_b, bn2_m, bn2_v,
        c3_w, c3_b, bn3_g, bn3_b, bn3_m, bn3_v, x3bf);
    // 4. fused FC+QKV MFMA -> Qb (B*T,144) fp32
    fc_qkv_mfma_kernel<<<960, 256, 0, stream>>>(x3bf, wp_bf, bp, Qb);
    // 5. attention -> attout (B*T,48), a_out (B,T,8,31)
    attn_kernel<<<dim3(T_ / 64, B_), 256, 0, stream>>>(Qb, rel, attout, a_out);
    // 6. LN + linear + sigmoid -> frame_pred (B,T,88)
    ln_kernel<<<(B_ * T_) / 32, 256, 0, stream>>>(attout, ln_g, ln_b, lin_w, lin_b,
                                                  frame_pred);
}

// Round 6
// 362.334 us; speedup vs baseline: 5.2768x; 1.2088x over previous
//
#include <hip/hip_runtime.h>
#include <hip/hip_bf16.h>
#include <math.h>

#define B_    8
#define T_    2560
#define F_    229
#define C1_   5
#define C2_   11
#define W1_   114
#define W2_   57
#define KP_   640
#define OF_   88
#define MC_   48
#define G_    8
#define DH_   6
#define K_    31
#define PAD_  15
#define BN_EPS 1e-5f
#define LN_EPS 1e-5f
#define TS_   8

typedef __attribute__((ext_vector_type(8))) short short8;
typedef __attribute__((ext_vector_type(4))) float f32x4;

static inline int cdiv(int a, int b) { return (a + b - 1) / b; }

__device__ inline float bflo(unsigned u) { return __uint_as_float(u << 16); }
__device__ inline float bfhi(unsigned u) { return __uint_as_float(u & 0xffff0000u); }

// ---------------- conv1: 1 -> 5, 3x3 SAME, + bn + relu -> bf16 ----------------
__global__ __launch_bounds__(256) void conv1_kernel(const float* __restrict__ spec,
        const float* __restrict__ w, const float* __restrict__ cb,
        const float* __restrict__ g, const float* __restrict__ bb,
        const float* __restrict__ m, const float* __restrict__ vv,
        __hip_bfloat16* __restrict__ out) {
    int idx = blockIdx.x * 256 + threadIdx.x;
    if (idx >= B_ * T_ * F_) return;
    int f = idx % F_;
    int t = (idx / F_) % T_;
    int b = idx / (F_ * T_);
    const float* sp = spec + (size_t)b * T_ * F_;
    float tap[3][3];
#pragma unroll
    for (int dt = 0; dt < 3; ++dt) {
        int tt = t + dt - 1;
        bool tv = (tt >= 0 && tt < T_);
#pragma unroll
        for (int df = 0; df < 3; ++df) {
            int ff = f + df - 1;
            tap[dt][df] = (tv && ff >= 0 && ff < F_) ? sp[(size_t)tt * F_ + ff] : 0.f;
        }
    }
#pragma unroll
    for (int co = 0; co < C1_; ++co) {
        float acc = 0.f;
#pragma unroll
        for (int k = 0; k < 9; ++k) acc = fmaf(tap[k / 3][k % 3], w[co * 9 + k], acc);
        float scl = g[co] * rsqrtf(vv[co] + BN_EPS);
        float y = (acc + cb[co] - m[co]) * scl + bb[co];
        out[((size_t)(b * C1_ + co) * T_ + t) * F_ + f] = __float2bfloat16(fmaxf(y, 0.f));
    }
}

// ------- fused conv2+pool+conv3+pool: x1bf (B,5,T,229) -> x3bf [bt][640] -------
// bf16 LDS tiles (43 KB -> 3 blocks/CU), fmaf-chained MACs, VGPR capped at 64.
__global__ __launch_bounds__(640, 8) void conv23_kernel(
        const __hip_bfloat16* __restrict__ x1bf,
        const float* __restrict__ c2w, const float* __restrict__ c2b,
        const float* __restrict__ g2, const float* __restrict__ b2,
        const float* __restrict__ m2, const float* __restrict__ v2,
        const float* __restrict__ c3w, const float* __restrict__ c3b,
        const float* __restrict__ g3, const float* __restrict__ b3,
        const float* __restrict__ m3, const float* __restrict__ v3,
        __hip_bfloat16* __restrict__ x3out) {
    __shared__ ushort x1t[12 * 5 * 232];         // 27,840 B (col = f+1, bf16)
    __shared__ ushort x2pt[10 * 5 * 120];        // 12,000 B (col = w+1, bf16)
    __shared__ float w2s[225], w3s[495];
    __shared__ float scl2[5], shf2[5], scl3[11], shf3[11];
    int t0 = blockIdx.x * TS_;
    int b = blockIdx.y;
    int tid = threadIdx.x;

    for (int i = tid; i < 225; i += 640) w2s[i] = c2w[i];
    for (int i = tid; i < 495; i += 640) w3s[i] = c3w[i];
    if (tid < 5) {
        float s = g2[tid] * rsqrtf(v2[tid] + BN_EPS);
        scl2[tid] = s;
        shf2[tid] = (c2b[tid] - m2[tid]) * s + b2[tid];
    }
    if (tid >= 64 && tid < 75) {
        int c = tid - 64;
        float s = g3[c] * rsqrtf(v3[c] + BN_EPS);
        scl3[c] = s;
        shf3[c] = (c3b[c] - m3[c]) * s + b3[c];
    }
    const ushort* x1u = (const ushort*)x1bf;
    for (int i = tid; i < 12 * 5 * 232; i += 640) {
        int col = i % 232;
        int ci = (i / 232) % 5;
        int rr = i / 1160;
        int t = t0 - 2 + rr;
        int f = col - 1;
        ushort v = 0;
        if (t >= 0 && t < T_ && f >= 0 && f < F_)
            v = x1u[((size_t)(b * 5 + ci) * T_ + t) * F_ + f];
        x1t[i] = v;
    }
    __syncthreads();

    // ---- phase 2: conv2+bn+relu+pool -> x2pt rows (t0-1 .. t0+8) ----
    if (tid < 570) {
        int co = tid / 114;
        int j = tid % 114;
        float acc0[10], acc1[10];
#pragma unroll
        for (int r = 0; r < 10; ++r) { acc0[r] = 0.f; acc1[r] = 0.f; }
#pragma unroll
        for (int ci = 0; ci < 5; ++ci) {
            float wr[9];
#pragma unroll
            for (int k = 0; k < 9; ++k) wr[k] = w2s[(co * 5 + ci) * 9 + k];
#pragma unroll
            for (int rr = 0; rr < 12; ++rr) {
                const uint2 u = *(const uint2*)&x1t[(rr * 5 + ci) * 232 + 2 * j];
                float v0 = bflo(u.x), v1 = bfhi(u.x), v2_ = bflo(u.y), v3_ = bfhi(u.y);
#pragma unroll
                for (int dt = 0; dt < 3; ++dt) {
                    int r = rr - dt;
                    if (r >= 0 && r < 10) {
                        acc0[r] = fmaf(v0, wr[dt * 3],
                                  fmaf(v1, wr[dt * 3 + 1],
                                  fmaf(v2_, wr[dt * 3 + 2], acc0[r])));
                        acc1[r] = fmaf(v1, wr[dt * 3],
                                  fmaf(v2_, wr[dt * 3 + 1],
                                  fmaf(v3_, wr[dt * 3 + 2], acc1[r])));
                    }
                }
            }
        }
        float s = scl2[co], sh = shf2[co];
#pragma unroll
        for (int r = 0; r < 10; ++r) {
            int t = t0 - 1 + r;
            float y = fmaxf(fmaxf(acc0[r] * s + sh, 0.f), fmaxf(acc1[r] * s + sh, 0.f));
            if (t < 0 || t >= T_) y = 0.f;
            __hip_bfloat16 h = __float2bfloat16(y);
            x2pt[(r * 5 + co) * 120 + 1 + j] = *(ushort*)&h;
        }
    } else {
        for (int i = tid - 570; i < 300; i += 70) {
            int cc = i % 6;
            int col = (cc == 0) ? 0 : 114 + cc;
            int ci = (i / 6) % 5;
            int r = i / 30;
            x2pt[(r * 5 + ci) * 120 + col] = 0;
        }
    }
    __syncthreads();

    // ---- phase 3: conv3+bn+relu+pool -> x3out bf16 [bt][640] ----
    if (tid < 627) {
        int co = tid / 57;
        int j = tid % 57;
        float acc0[8], acc1[8];
#pragma unroll
        for (int r = 0; r < 8; ++r) { acc0[r] = 0.f; acc1[r] = 0.f; }
#pragma unroll
        for (int ci = 0; ci < 5; ++ci) {
            float wr[9];
#pragma unroll
            for (int k = 0; k < 9; ++k) wr[k] = w3s[(co * 5 + ci) * 9 + k];
#pragma unroll
            for (int rr = 0; rr < 10; ++rr) {
                const uint2 u = *(const uint2*)&x2pt[(rr * 5 + ci) * 120 + 2 * j];
                float v0 = bflo(u.x), v1 = bfhi(u.x), v2_ = bflo(u.y), v3_ = bfhi(u.y);
#pragma unroll
                for (int dt = 0; dt < 3; ++dt) {
                    int r = rr - dt;
                    if (r >= 0 && r < 8) {
                        acc0[r] = fmaf(v0, wr[dt * 3],
                                  fmaf(v1, wr[dt * 3 + 1],
                                  fmaf(v2_, wr[dt * 3 + 2], acc0[r])));
                        acc1[r] = fmaf(v1, wr[dt * 3],
                                  fmaf(v2_, wr[dt * 3 + 1],
                                  fmaf(v3_, wr[dt * 3 + 2], acc1[r])));
                    }
                }
            }
        }
        float s = scl3[co], sh = shf3[co];
#pragma unroll
        for (int r = 0; r < 8; ++r) {
            float y0 = fmaxf(acc0[r] * s + sh, 0.f);
            float y1 = fmaxf(acc1[r] * s + sh, 0.f);
            x3out[(size_t)(b * T_ + t0 + r) * KP_ + co * 57 + j] =
                __float2bfloat16(fmaxf(y0, y1));
        }
    } else {
        __hip_bfloat16 z = __float2bfloat16(0.f);
#pragma unroll
        for (int r = 0; r < 8; ++r)
            x3out[(size_t)(b * T_ + t0 + r) * KP_ + tid] = z;
    }
}

// -------- W' = [wq;wk;wv] @ fc_w -> bf16 [144][640] (padded), b' fp32 --------
__global__ __launch_bounds__(256) void wprime_kernel(const float* __restrict__ fc_w,
        const float* __restrict__ fc_b, const float* __restrict__ wq,
        const float* __restrict__ wk, const float* __restrict__ wv,
        __hip_bfloat16* __restrict__ wp, float* __restrict__ bp) {
    int idx = blockIdx.x * 256 + threadIdx.x;
    if (idx < 144 * KP_) {
        int o = idx / KP_;
        int kk = idx % KP_;
        const float* Wrow = (o < 48) ? (wq + o * 88)
                          : (o < 96) ? (wk + (o - 48) * 88) : (wv + (o - 96) * 88);
        float s = 0.f;
        if (kk < 627)
            for (int i = 0; i < 88; ++i) s = fmaf(Wrow[i], fc_w[(size_t)i * 627 + kk], s);
        wp[idx] = __float2bfloat16(s);
    } else if (idx < 144 * KP_ + 144) {
        int o = idx - 144 * KP_;
        const float* Wrow = (o < 48) ? (wq + o * 88)
                          : (o < 96) ? (wk + (o - 48) * 88) : (wv + (o - 96) * 88);
        float s = 0.f;
        for (int i = 0; i < 88; ++i) s = fmaf(Wrow[i], fc_b[i], s);
        bp[o] = s;
    }
}

// -------- fused FC+QKV via MFMA bf16: Q[bt][144] = X[bt][640] @ W'^T + b' --------
__global__ __launch_bounds__(256) void fc_qkv_mfma_kernel(
        const __hip_bfloat16* __restrict__ X, const __hip_bfloat16* __restrict__ Wp,
        const float* __restrict__ bp, float* __restrict__ Q) {
    int tid = threadIdx.x;
    int lane = tid & 63;
    int gw = blockIdx.x * 4 + (tid >> 6);
    int mtile = gw / 3;
    int nthird = gw % 3;
    const short* Xs = (const short*)X;
    const short* Ws = (const short*)Wp;
    int klane = (lane >> 4) * 8;
    const short* xrow = Xs + (size_t)(mtile * 16 + (lane & 15)) * KP_ + klane;
    const short* wrow = Ws + (size_t)(nthird * 48 + (lane & 15)) * KP_ + klane;
    f32x4 acc0 = {0.f, 0.f, 0.f, 0.f}, acc1 = acc0, acc2 = acc0;
#pragma unroll 4
    for (int kt = 0; kt < 20; ++kt) {
        short8 a = *(const short8*)(xrow + kt * 32);
        short8 b0 = *(const short8*)(wrow + kt * 32);
        short8 b1 = *(const short8*)(wrow + 16 * KP_ + kt * 32);
        short8 b2 = *(const short8*)(wrow + 32 * KP_ + kt * 32);
        acc0 = __builtin_amdgcn_mfma_f32_16x16x32_bf16(a, b0, acc0, 0, 0, 0);
        acc1 = __builtin_amdgcn_mfma_f32_16x16x32_bf16(a, b1, acc1, 0, 0, 0);
        acc2 = __builtin_amdgcn_mfma_f32_16x16x32_bf16(a, b2, acc2, 0, 0, 0);
    }
    int r0 = mtile * 16 + (lane >> 4) * 4;
    int col = lane & 15;
    f32x4 accs[3] = {acc0, acc1, acc2};
#pragma unroll
    for (int nt = 0; nt < 3; ++nt) {
        int o = nthird * 48 + nt * 16 + col;
        float bias = bp[o];
#pragma unroll
        for (int rg = 0; rg < 4; ++rg)
            Q[(size_t)(r0 + rg) * 144 + o] = accs[nt][rg] + bias;
    }
}

// ---------------- windowed relative attention, 32-t tiles ----------------
// kvt row stride 100 (pad) so the tl-major lane layout spreads banks.
__global__ __launch_bounds__(256) void attn_kernel(const float* __restrict__ Q,
        const float* __restrict__ rel, float* __restrict__ attout,
        float* __restrict__ aout) {
    __shared__ float kvt[62 * 100];      // rows t0-15..t0+46; col 0..47=k, 48..95=v
    __shared__ float qt[32 * 52];
    __shared__ float relT[31 * 48];      // [kp][j]
    int b = blockIdx.y;
    int t0 = blockIdx.x * 32;
    int tid = threadIdx.x;
    // stage k/v (Q cols 48..143) as float2
    for (int i = tid; i < 62 * 48; i += 256) {
        int row = i / 48, c2 = i % 48;
        int t = t0 - 15 + row;
        float2 v = {0.f, 0.f};
        if (t >= 0 && t < T_)
            v = *(const float2*)&Q[((size_t)b * T_ + t) * 144 + 48 + 2 * c2];
        *(float2*)&kvt[row * 100 + 2 * c2] = v;
    }
    // stage q (cols 0..47)
    for (int i = tid; i < 32 * 24; i += 256) {
        int row = i / 24, c2 = i % 24;
        float2 v = *(const float2*)&Q[((size_t)b * T_ + t0 + row) * 144 + 2 * c2];
        *(float2*)&qt[row * 52 + 2 * c2] = v;
    }
    for (int i = tid; i < 31 * 48; i += 256) {
        int kp = i / 48, j = i % 48;
        relT[i] = rel[j * 31 + kp];
    }
    __syncthreads();
    int g = tid & 7;
    int tl = tid >> 3;
    const float* qp = &qt[tl * 52 + g * 6];
    float2 q01 = *(const float2*)qp;
    float2 q23 = *(const float2*)(qp + 2);
    float2 q45 = *(const float2*)(qp + 4);
    float e[31];
    float emax = -1e30f;
#pragma unroll
    for (int kp = 0; kp < 31; ++kp) {
        const float* kr = &kvt[(tl + kp) * 100 + g * 6];
        const float* rr = &relT[kp * 48 + g * 6];
        float2 k01 = *(const float2*)kr;
        float2 k23 = *(const float2*)(kr + 2);
        float2 k45 = *(const float2*)(kr + 4);
        float2 r01 = *(const float2*)rr;
        float2 r23 = *(const float2*)(rr + 2);
        float2 r45 = *(const float2*)(rr + 4);
        float s = fmaf(q01.x, k01.x + r01.x,
                  fmaf(q01.y, k01.y + r01.y,
                  fmaf(q23.x, k23.x + r23.x,
                  fmaf(q23.y, k23.y + r23.y,
                  fmaf(q45.x, k45.x + r45.x,
                       q45.y * (k45.y + r45.y))))));
        e[kp] = s;
        emax = fmaxf(emax, s);
    }
    float sum = 0.f;
#pragma unroll
    for (int kp = 0; kp < 31; ++kp) { e[kp] = __expf(e[kp] - emax); sum += e[kp]; }
    float inv = 1.f / sum;
    int t = t0 + tl;
    float* ap = &aout[(((size_t)b * T_ + t) * 8 + g) * 31];
    float o0 = 0, o1 = 0, o2 = 0, o3 = 0, o4 = 0, o5 = 0;
#pragma unroll
    for (int kp = 0; kp < 31; ++kp) {
        float a = e[kp] * inv;
        ap[kp] = a;
        const float* vr = &kvt[(tl + kp) * 100 + 48 + g * 6];
        float2 v01 = *(const float2*)vr;
        float2 v23 = *(const float2*)(vr + 2);
        float2 v45 = *(const float2*)(vr + 4);
        o0 = fmaf(a, v01.x, o0); o1 = fmaf(a, v01.y, o1);
        o2 = fmaf(a, v23.x, o2); o3 = fmaf(a, v23.y, o3);
        o4 = fmaf(a, v45.x, o4); o5 = fmaf(a, v45.y, o5);
    }
    float* op = &attout[((size_t)b * T_ + t) * 48 + g * 6];
    op[0] = o0; op[1] = o1; op[2] = o2; op[3] = o3; op[4] = o4; op[5] = o5;
}

// ---------- LayerNorm(48) + linear(48->88) + sigmoid, 32 rows/block ----------
__global__ __launch_bounds__(256) void ln_kernel(const float* __restrict__ att,
        const float* __restrict__ lng, const float* __restrict__ lnb,
        const float* __restrict__ lw, const float* __restrict__ lb,
        float* __restrict__ fp) {
    __shared__ float xr[32 * 48];
    __shared__ float wl[88 * 48];
    __shared__ float mus[32], rss[32], gs[48], bs[48], lbs[88];
    int row0 = blockIdx.x * 32;
    int tid = threadIdx.x;
    for (int i = tid; i < 32 * 48; i += 256) xr[i] = att[(size_t)row0 * 48 + i];
    for (int i = tid; i < 88 * 48; i += 256) wl[i] = lw[i];
    if (tid < 48) { gs[tid] = lng[tid]; bs[tid] = lnb[tid]; }
    if (tid < 88) lbs[tid] = lb[tid];
    __syncthreads();
    if (tid < 32) {
        float s = 0.f;
        for (int c = 0; c < 48; ++c) s += xr[tid * 48 + c];
        float mu = s * (1.f / 48.f);
        float v2 = 0.f;
        for (int c = 0; c < 48; ++c) { float d = xr[tid * 48 + c] - mu; v2 = fmaf(d, d, v2); }
        mus[tid] = mu;
        rss[tid] = rsqrtf(v2 * (1.f / 48.f) + LN_EPS);
    }
    __syncthreads();
    for (int i = tid; i < 32 * 48; i += 256) {
        int r = i / 48, c = i % 48;
        xr[i] = fmaf((xr[i] - mus[r]) * rss[r], gs[c], bs[c]);
    }
    __syncthreads();
    for (int k = 0; k < 11; ++k) {
        int cid = k * 256 + tid;
        int o = cid % 88, r = cid / 88;
        const float* xp = &xr[r * 48];
        const float* wpp = &wl[o * 48];
        float s = lbs[o];
#pragma unroll
        for (int c = 0; c < 48; c += 4) {
            float4 xv = *(const float4*)&xp[c];
            float4 wv = *(const float4*)&wpp[c];
            s = fmaf(xv.x, wv.x, s);
            s = fmaf(xv.y, wv.y, s);
            s = fmaf(xv.z, wv.z, s);
            s = fmaf(xv.w, wv.w, s);
        }
        fp[(size_t)row0 * 88 + cid] = 1.f / (1.f + __expf(-s));
    }
}

extern "C" void kernel_launch(void* const* d_in, const int* in_sizes, int n_in,
                              void* d_out, int out_size, void* d_ws, size_t ws_size,
                              hipStream_t stream) {
    const float* spec = (const float*)d_in[0];
    const float* c1_w = (const float*)d_in[1];
    const float* c1_b = (const float*)d_in[2];
    const float* bn1_g = (const float*)d_in[3];
    const float* bn1_b = (const float*)d_in[4];
    const float* bn1_m = (const float*)d_in[5];
    const float* bn1_v = (const float*)d_in[6];
    const float* c2_w = (const float*)d_in[7];
    const float* c2_b = (const float*)d_in[8];
    const float* bn2_g = (const float*)d_in[9];
    const float* bn2_b = (const float*)d_in[10];
    const float* bn2_m = (const float*)d_in[11];
    const float* bn2_v = (const float*)d_in[12];
    const float* c3_w = (const float*)d_in[13];
    const float* c3_b = (const float*)d_in[14];
    const float* bn3_g = (const float*)d_in[15];
    const float* bn3_b = (const float*)d_in[16];
    const float* bn3_m = (const float*)d_in[17];
    const float* bn3_v = (const float*)d_in[18];
    const float* fc_w = (const float*)d_in[19];
    const float* fc_b = (const float*)d_in[20];
    const float* wq = (const float*)d_in[21];
    const float* wk = (const float*)d_in[22];
    const float* wv = (const float*)d_in[23];
    const float* rel = (const float*)d_in[24];
    const float* ln_g = (const float*)d_in[25];
    const float* ln_b = (const float*)d_in[26];
    const float* lin_w = (const float*)d_in[27];
    const float* lin_b = (const float*)d_in[28];

    float* ws = (float*)d_ws;
    __hip_bfloat16* x3bf = (__hip_bfloat16*)ws;                 // 13.1M bf16
    __hip_bfloat16* x1bf = (__hip_bfloat16*)(ws + 7000000);     // 23.45M bf16
    __hip_bfloat16* wp_bf = (__hip_bfloat16*)(ws + 19000000);
    float* bp = ws + 19100000;
    float* regB = ws + 23449600;
    float* Qb = regB;
    float* attout = regB + 3000000;

    float* frame_pred = (float*)d_out;
    float* a_out = frame_pred + (size_t)B_ * T_ * OF_;

    conv1_kernel<<<cdiv(B_ * T_ * F_, 256), 256, 0, stream>>>(spec, c1_w, c1_b, bn1_g,
                                                              bn1_b, bn1_m, bn1_v, x1bf);
    wprime_kernel<<<cdiv(144 * KP_ + 144, 256), 256, 0, stream>>>(fc_w, fc_b, wq, wk, wv,
                                                                  wp_bf, bp);
    conv23_kernel<<<dim3(T_ / TS_, B_), 640, 0, stream>>>(
        x1bf, c2_w, c2_b, bn2_g, bn2_b, bn2_m, bn2_v,
        c3_w, c3_b, bn3_g, bn3_b, bn3_m, bn3_v, x3bf);
    fc_qkv_mfma_kernel<<<960, 256, 0, stream>>>(x3bf, wp_bf, bp, Qb);
    attn_kernel<<<dim3(T_ / 32, B_), 256, 0, stream>>>(Qb, rel, attout, a_out);
    ln_kernel<<<(B_ * T_) / 32, 256, 0, stream>>>(attout, ln_g, ln_b, lin_w, lin_b,
                                                  frame_pred);
}

// Round 7
// 360.153 us; speedup vs baseline: 5.3088x; 1.0061x over previous
//
#include <hip/hip_runtime.h>
#include <hip/hip_bf16.h>
#include <math.h>

#define B_    8
#define T_    2560
#define F_    229
#define C1_   5
#define C2_   11
#define W1_   114
#define W2_   57
#define KP_   640
#define OF_   88
#define MC_   48
#define G_    8
#define DH_   6
#define K_    31
#define PAD_  15
#define BN_EPS 1e-5f
#define LN_EPS 1e-5f
#define TS_   8

typedef __attribute__((ext_vector_type(8))) short short8;
typedef __attribute__((ext_vector_type(4))) float f32x4;

static inline int cdiv(int a, int b) { return (a + b - 1) / b; }

__device__ inline float bflo(unsigned u) { return __uint_as_float(u << 16); }
__device__ inline float bfhi(unsigned u) { return __uint_as_float(u & 0xffff0000u); }

// ---- fused conv1+conv2+pool+conv3+pool: spec (B,T,229) -> x3bf [bt][640] ----
// Phase 1: stage spec tile, compute x1 (conv1+bn+relu) into fp32 LDS tile.
// Phase 2: conv2+bn+relu+pool -> bf16 x2p tile (unions with spec tile).
// Phase 3: conv3+bn+relu+pool -> global bf16 MFMA layout.
__global__ __launch_bounds__(640, 4) void conv123_kernel(
        const float* __restrict__ spec,
        const float* __restrict__ c1w, const float* __restrict__ c1b,
        const float* __restrict__ g1, const float* __restrict__ b1,
        const float* __restrict__ m1, const float* __restrict__ v1,
        const float* __restrict__ c2w, const float* __restrict__ c2b,
        const float* __restrict__ g2, const float* __restrict__ b2,
        const float* __restrict__ m2, const float* __restrict__ v2,
        const float* __restrict__ c3w, const float* __restrict__ c3b,
        const float* __restrict__ g3, const float* __restrict__ b3,
        const float* __restrict__ m3, const float* __restrict__ v3,
        __hip_bfloat16* __restrict__ x3out) {
    __shared__ float x1t[12 * 5 * 232];      // 55,680 B fp32 (col = f+1)
    __shared__ float specx2[14 * 232];       // 12,992 B: spec tile, then x2p bf16 tile
    __shared__ float w1s[45], w2s[225], w3s[495];
    __shared__ float scl1[5], shf1[5], scl2[5], shf2[5], scl3[11], shf3[11];
    int t0 = blockIdx.x * TS_;
    int b = blockIdx.y;
    int tid = threadIdx.x;

    if (tid < 45) w1s[tid] = c1w[tid];
    for (int i = tid; i < 225; i += 640) w2s[i] = c2w[i];
    for (int i = tid; i < 495; i += 640) w3s[i] = c3w[i];
    if (tid < 5) {
        float s = g1[tid] * rsqrtf(v1[tid] + BN_EPS);
        scl1[tid] = s;
        shf1[tid] = (c1b[tid] - m1[tid]) * s + b1[tid];
    }
    if (tid >= 64 && tid < 69) {
        int c = tid - 64;
        float s = g2[c] * rsqrtf(v2[c] + BN_EPS);
        scl2[c] = s;
        shf2[c] = (c2b[c] - m2[c]) * s + b2[c];
    }
    if (tid >= 128 && tid < 139) {
        int c = tid - 128;
        float s = g3[c] * rsqrtf(v3[c] + BN_EPS);
        scl3[c] = s;
        shf3[c] = (c3b[c] - m3[c]) * s + b3[c];
    }
    // stage spec rows t0-3 .. t0+10 (zero-padded), col = f+1
    {
        const float* sb = spec + (size_t)b * T_ * F_;
        for (int i = tid; i < 14 * 232; i += 640) {
            int col = i % 232;
            int rr = i / 232;
            int t = t0 - 3 + rr;
            int f = col - 1;
            float v = 0.f;
            if (t >= 0 && t < T_ && f >= 0 && f < F_) v = sb[(size_t)t * F_ + f];
            specx2[i] = v;
        }
    }
    __syncthreads();

    // ---- phase 1: conv1+bn+relu -> x1t rows t0-2..t0+9 (fp32) ----
    for (int i = tid; i < 12 * 229; i += 640) {
        int f = i % 229;
        int rr = i / 229;
        int t = t0 - 2 + rr;
        float y[5];
        if (t >= 0 && t < T_) {
            float tp[9];
#pragma unroll
            for (int dt = 0; dt < 3; ++dt) {
                const float* row = &specx2[(rr + dt) * 232 + f];
                tp[dt * 3 + 0] = row[0];
                tp[dt * 3 + 1] = row[1];
                tp[dt * 3 + 2] = row[2];
            }
#pragma unroll
            for (int co = 0; co < 5; ++co) {
                float acc = 0.f;
#pragma unroll
                for (int k = 0; k < 9; ++k) acc = fmaf(tp[k], w1s[co * 9 + k], acc);
                y[co] = fmaxf(fmaf(acc, scl1[co], shf1[co]), 0.f);
            }
        } else {
#pragma unroll
            for (int co = 0; co < 5; ++co) y[co] = 0.f;
        }
#pragma unroll
        for (int co = 0; co < 5; ++co) x1t[(rr * 5 + co) * 232 + 1 + f] = y[co];
    }
    // zero x1t pad cols 0, 230, 231
    for (int i = tid; i < 180; i += 640) {
        int c = i % 3;
        int col = (c == 0) ? 0 : 229 + c;
        int ci = (i / 3) % 5;
        int rr = i / 15;
        x1t[(rr * 5 + ci) * 232 + col] = 0.f;
    }
    __syncthreads();

    // ---- phase 2: conv2+bn+relu+pool -> x2pt (bf16, unions with spec tile) ----
    ushort* x2pt = (ushort*)specx2;          // 10 rows x 5 ci x 120 (col = w+1)
    if (tid < 570) {
        int co = tid / 114;
        int j = tid % 114;
        float acc0[10], acc1[10];
#pragma unroll
        for (int r = 0; r < 10; ++r) { acc0[r] = 0.f; acc1[r] = 0.f; }
#pragma unroll
        for (int ci = 0; ci < 5; ++ci) {
            float wr[9];
#pragma unroll
            for (int k = 0; k < 9; ++k) wr[k] = w2s[(co * 5 + ci) * 9 + k];
#pragma unroll
            for (int rr = 0; rr < 12; ++rr) {
                const float* p = &x1t[(rr * 5 + ci) * 232 + 2 * j];
                float2 a = *(const float2*)p;
                float2 bq = *(const float2*)(p + 2);
                float v0 = a.x, v1 = a.y, v2_ = bq.x, v3_ = bq.y;
#pragma unroll
                for (int dt = 0; dt < 3; ++dt) {
                    int r = rr - dt;
                    if (r >= 0 && r < 10) {
                        acc0[r] = fmaf(v0, wr[dt * 3],
                                  fmaf(v1, wr[dt * 3 + 1],
                                  fmaf(v2_, wr[dt * 3 + 2], acc0[r])));
                        acc1[r] = fmaf(v1, wr[dt * 3],
                                  fmaf(v2_, wr[dt * 3 + 1],
                                  fmaf(v3_, wr[dt * 3 + 2], acc1[r])));
                    }
                }
            }
        }
        float s = scl2[co], sh = shf2[co];
        float yv[10];
#pragma unroll
        for (int r = 0; r < 10; ++r) {
            int t = t0 - 1 + r;
            float y = fmaxf(fmaxf(acc0[r] * s + sh, 0.f), fmaxf(acc1[r] * s + sh, 0.f));
            yv[r] = (t < 0 || t >= T_) ? 0.f : y;
        }
        __syncthreads();                      // spec tile dead; safe to overwrite
#pragma unroll
        for (int r = 0; r < 10; ++r) {
            __hip_bfloat16 h = __float2bfloat16(yv[r]);
            x2pt[(r * 5 + co) * 120 + 1 + j] = *(ushort*)&h;
        }
    } else {
        __syncthreads();
        for (int i = tid - 570; i < 300; i += 70) {
            int cc = i % 6;
            int col = (cc == 0) ? 0 : 114 + cc;
            int ci = (i / 6) % 5;
            int r = i / 30;
            x2pt[(r * 5 + ci) * 120 + col] = 0;
        }
    }
    __syncthreads();

    // ---- phase 3: conv3+bn+relu+pool -> x3out bf16 [bt][640] ----
    if (tid < 627) {
        int co = tid / 57;
        int j = tid % 57;
        float acc0[8], acc1[8];
#pragma unroll
        for (int r = 0; r < 8; ++r) { acc0[r] = 0.f; acc1[r] = 0.f; }
#pragma unroll
        for (int ci = 0; ci < 5; ++ci) {
            float wr[9];
#pragma unroll
            for (int k = 0; k < 9; ++k) wr[k] = w3s[(co * 5 + ci) * 9 + k];
#pragma unroll
            for (int rr = 0; rr < 10; ++rr) {
                const ushort* p = &x2pt[(rr * 5 + ci) * 120 + 2 * j];
                unsigned u0 = *(const unsigned*)p;
                unsigned u1 = *(const unsigned*)(p + 2);
                float v0 = bflo(u0), v1 = bfhi(u0), v2_ = bflo(u1), v3_ = bfhi(u1);
#pragma unroll
                for (int dt = 0; dt < 3; ++dt) {
                    int r = rr - dt;
                    if (r >= 0 && r < 8) {
                        acc0[r] = fmaf(v0, wr[dt * 3],
                                  fmaf(v1, wr[dt * 3 + 1],
                                  fmaf(v2_, wr[dt * 3 + 2], acc0[r])));
                        acc1[r] = fmaf(v1, wr[dt * 3],
                                  fmaf(v2_, wr[dt * 3 + 1],
                                  fmaf(v3_, wr[dt * 3 + 2], acc1[r])));
                    }
                }
            }
        }
        float s = scl3[co], sh = shf3[co];
#pragma unroll
        for (int r = 0; r < 8; ++r) {
            float y0 = fmaxf(acc0[r] * s + sh, 0.f);
            float y1 = fmaxf(acc1[r] * s + sh, 0.f);
            x3out[(size_t)(b * T_ + t0 + r) * KP_ + co * 57 + j] =
                __float2bfloat16(fmaxf(y0, y1));
        }
    } else if (tid >= 627 && tid < 640) {
        __hip_bfloat16 z = __float2bfloat16(0.f);
#pragma unroll
        for (int r = 0; r < 8; ++r)
            x3out[(size_t)(b * T_ + t0 + r) * KP_ + tid] = z;
    }
}

// -------- W' = [wq;wk;wv] @ fc_w -> bf16 [144][640] (padded), b' fp32 --------
__global__ __launch_bounds__(256) void wprime_kernel(const float* __restrict__ fc_w,
        const float* __restrict__ fc_b, const float* __restrict__ wq,
        const float* __restrict__ wk, const float* __restrict__ wv,
        __hip_bfloat16* __restrict__ wp, float* __restrict__ bp) {
    int idx = blockIdx.x * 256 + threadIdx.x;
    if (idx < 144 * KP_) {
        int o = idx / KP_;
        int kk = idx % KP_;
        const float* Wrow = (o < 48) ? (wq + o * 88)
                          : (o < 96) ? (wk + (o - 48) * 88) : (wv + (o - 96) * 88);
        float s = 0.f;
        if (kk < 627)
            for (int i = 0; i < 88; ++i) s = fmaf(Wrow[i], fc_w[(size_t)i * 627 + kk], s);
        wp[idx] = __float2bfloat16(s);
    } else if (idx < 144 * KP_ + 144) {
        int o = idx - 144 * KP_;
        const float* Wrow = (o < 48) ? (wq + o * 88)
                          : (o < 96) ? (wk + (o - 48) * 88) : (wv + (o - 96) * 88);
        float s = 0.f;
        for (int i = 0; i < 88; ++i) s = fmaf(Wrow[i], fc_b[i], s);
        bp[o] = s;
    }
}

// -------- fused FC+QKV via MFMA bf16: Q[bt][144] = X[bt][640] @ W'^T + b' --------
__global__ __launch_bounds__(256) void fc_qkv_mfma_kernel(
        const __hip_bfloat16* __restrict__ X, const __hip_bfloat16* __restrict__ Wp,
        const float* __restrict__ bp, float* __restrict__ Q) {
    int tid = threadIdx.x;
    int lane = tid & 63;
    int gw = blockIdx.x * 4 + (tid >> 6);
    int mtile = gw / 3;
    int nthird = gw % 3;
    const short* Xs = (const short*)X;
    const short* Ws = (const short*)Wp;
    int klane = (lane >> 4) * 8;
    const short* xrow = Xs + (size_t)(mtile * 16 + (lane & 15)) * KP_ + klane;
    const short* wrow = Ws + (size_t)(nthird * 48 + (lane & 15)) * KP_ + klane;
    f32x4 acc0 = {0.f, 0.f, 0.f, 0.f}, acc1 = acc0, acc2 = acc0;
#pragma unroll 4
    for (int kt = 0; kt < 20; ++kt) {
        short8 a = *(const short8*)(xrow + kt * 32);
        short8 b0 = *(const short8*)(wrow + kt * 32);
        short8 b1 = *(const short8*)(wrow + 16 * KP_ + kt * 32);
        short8 b2 = *(const short8*)(wrow + 32 * KP_ + kt * 32);
        acc0 = __builtin_amdgcn_mfma_f32_16x16x32_bf16(a, b0, acc0, 0, 0, 0);
        acc1 = __builtin_amdgcn_mfma_f32_16x16x32_bf16(a, b1, acc1, 0, 0, 0);
        acc2 = __builtin_amdgcn_mfma_f32_16x16x32_bf16(a, b2, acc2, 0, 0, 0);
    }
    int r0 = mtile * 16 + (lane >> 4) * 4;
    int col = lane & 15;
    f32x4 accs[3] = {acc0, acc1, acc2};
#pragma unroll
    for (int nt = 0; nt < 3; ++nt) {
        int o = nthird * 48 + nt * 16 + col;
        float bias = bp[o];
#pragma unroll
        for (int rg = 0; rg < 4; ++rg)
            Q[(size_t)(r0 + rg) * 144 + o] = accs[nt][rg] + bias;
    }
}

// ---------------- windowed relative attention, 32-t tiles ----------------
// a-matrix staged to LDS (reusing k/v tile) then written coalesced as float4.
__global__ __launch_bounds__(256) void attn_kernel(const float* __restrict__ Q,
        const float* __restrict__ rel, float* __restrict__ attout,
        float* __restrict__ aout) {
    __shared__ float smem[9352];
    float* kvt = smem;              // 62 rows x 100 (k: 0..47, v: 48..95)
    float* qt = smem + 6200;        // 32 x 52
    float* relT = smem + 7864;      // 31 x 48
    int b = blockIdx.y;
    int t0 = blockIdx.x * 32;
    int tid = threadIdx.x;
    for (int i = tid; i < 62 * 48; i += 256) {
        int row = i / 48, c2 = i % 48;
        int t = t0 - 15 + row;
        float2 v = {0.f, 0.f};
        if (t >= 0 && t < T_)
            v = *(const float2*)&Q[((size_t)b * T_ + t) * 144 + 48 + 2 * c2];
        *(float2*)&kvt[row * 100 + 2 * c2] = v;
    }
    for (int i = tid; i < 32 * 24; i += 256) {
        int row = i / 24, c2 = i % 24;
        float2 v = *(const float2*)&Q[((size_t)b * T_ + t0 + row) * 144 + 2 * c2];
        *(float2*)&qt[row * 52 + 2 * c2] = v;
    }
    for (int i = tid; i < 31 * 48; i += 256) {
        int kp = i / 48, j = i % 48;
        relT[i] = rel[j * 31 + kp];
    }
    __syncthreads();
    int g = tid & 7;
    int tl = tid >> 3;
    const float* qp = &qt[tl * 52 + g * 6];
    float2 q01 = *(const float2*)qp;
    float2 q23 = *(const float2*)(qp + 2);
    float2 q45 = *(const float2*)(qp + 4);
    float e[31];
    float emax = -1e30f;
#pragma unroll
    for (int kp = 0; kp < 31; ++kp) {
        const float* kr = &kvt[(tl + kp) * 100 + g * 6];
        const float* rr = &relT[kp * 48 + g * 6];
        float2 k01 = *(const float2*)kr;
        float2 k23 = *(const float2*)(kr + 2);
        float2 k45 = *(const float2*)(kr + 4);
        float2 r01 = *(const float2*)rr;
        float2 r23 = *(const float2*)(rr + 2);
        float2 r45 = *(const float2*)(rr + 4);
        float s = fmaf(q01.x, k01.x + r01.x,
                  fmaf(q01.y, k01.y + r01.y,
                  fmaf(q23.x, k23.x + r23.x,
                  fmaf(q23.y, k23.y + r23.y,
                  fmaf(q45.x, k45.x + r45.x,
                       q45.y * (k45.y + r45.y))))));
        e[kp] = s;
        emax = fmaxf(emax, s);
    }
    float sum = 0.f;
#pragma unroll
    for (int kp = 0; kp < 31; ++kp) { e[kp] = __expf(e[kp] - emax); sum += e[kp]; }
    float inv = 1.f / sum;
    float o0 = 0, o1 = 0, o2 = 0, o3 = 0, o4 = 0, o5 = 0;
#pragma unroll
    for (int kp = 0; kp < 31; ++kp) {
        float a = e[kp] * inv;
        e[kp] = a;
        const float* vr = &kvt[(tl + kp) * 100 + 48 + g * 6];
        float2 v01 = *(const float2*)vr;
        float2 v23 = *(const float2*)(vr + 2);
        float2 v45 = *(const float2*)(vr + 4);
        o0 = fmaf(a, v01.x, o0); o1 = fmaf(a, v01.y, o1);
        o2 = fmaf(a, v23.x, o2); o3 = fmaf(a, v23.y, o3);
        o4 = fmaf(a, v45.x, o4); o5 = fmaf(a, v45.y, o5);
    }
    int t = t0 + tl;
    float* op = &attout[((size_t)b * T_ + t) * 48 + g * 6];
    float2 w01 = {o0, o1}, w23 = {o2, o3}, w45 = {o4, o5};
    *(float2*)op = w01;
    *(float2*)(op + 2) = w23;
    *(float2*)(op + 4) = w45;
    __syncthreads();                 // done reading kvt; reuse as a-buffer
    float* abuf = smem;              // 256 threads x 31 floats = 7936
#pragma unroll
    for (int kp = 0; kp < 31; ++kp) abuf[tid * 31 + kp] = e[kp];
    __syncthreads();
    size_t base = ((size_t)b * T_ + t0) * 248;
    for (int i = tid; i < 1984; i += 256) {
        float4 v = *(const float4*)&abuf[4 * i];
        *(float4*)&aout[base + 4 * i] = v;
    }
}

// ---------- LayerNorm(48) + linear(48->88) + sigmoid, 32 rows/block ----------
__global__ __launch_bounds__(256) void ln_kernel(const float* __restrict__ att,
        const float* __restrict__ lng, const float* __restrict__ lnb,
        const float* __restrict__ lw, const float* __restrict__ lb,
        float* __restrict__ fp) {
    __shared__ float xr[32 * 48];
    __shared__ float wl[88 * 48];
    __shared__ float mus[32], rss[32], gs[48], bs[48], lbs[88];
    int row0 = blockIdx.x * 32;
    int tid = threadIdx.x;
    for (int i = tid; i < 32 * 48; i += 256) xr[i] = att[(size_t)row0 * 48 + i];
    for (int i = tid; i < 88 * 48; i += 256) wl[i] = lw[i];
    if (tid < 48) { gs[tid] = lng[tid]; bs[tid] = lnb[tid]; }
    if (tid < 88) lbs[tid] = lb[tid];
    __syncthreads();
    if (tid < 32) {
        float s = 0.f;
        for (int c = 0; c < 48; ++c) s += xr[tid * 48 + c];
        float mu = s * (1.f / 48.f);
        float v2 = 0.f;
        for (int c = 0; c < 48; ++c) { float d = xr[tid * 48 + c] - mu; v2 = fmaf(d, d, v2); }
        mus[tid] = mu;
        rss[tid] = rsqrtf(v2 * (1.f / 48.f) + LN_EPS);
    }
    __syncthreads();
    for (int i = tid; i < 32 * 48; i += 256) {
        int r = i / 48, c = i % 48;
        xr[i] = fmaf((xr[i] - mus[r]) * rss[r], gs[c], bs[c]);
    }
    __syncthreads();
    for (int k = 0; k < 11; ++k) {
        int cid = k * 256 + tid;
        int o = cid % 88, r = cid / 88;
        const float* xp = &xr[r * 48];
        const float* wpp = &wl[o * 48];
        float s = lbs[o];
#pragma unroll
        for (int c = 0; c < 48; c += 4) {
            float4 xv = *(const float4*)&xp[c];
            float4 wv = *(const float4*)&wpp[c];
            s = fmaf(xv.x, wv.x, s);
            s = fmaf(xv.y, wv.y, s);
            s = fmaf(xv.z, wv.z, s);
            s = fmaf(xv.w, wv.w, s);
        }
        fp[(size_t)row0 * 88 + cid] = 1.f / (1.f + __expf(-s));
    }
}

extern "C" void kernel_launch(void* const* d_in, const int* in_sizes, int n_in,
                              void* d_out, int out_size, void* d_ws, size_t ws_size,
                              hipStream_t stream) {
    const float* spec = (const float*)d_in[0];
    const float* c1_w = (const float*)d_in[1];
    const float* c1_b = (const float*)d_in[2];
    const float* bn1_g = (const float*)d_in[3];
    const float* bn1_b = (const float*)d_in[4];
    const float* bn1_m = (const float*)d_in[5];
    const float* bn1_v = (const float*)d_in[6];
    const float* c2_w = (const float*)d_in[7];
    const float* c2_b = (const float*)d_in[8];
    const float* bn2_g = (const float*)d_in[9];
    const float* bn2_b = (const float*)d_in[10];
    const float* bn2_m = (const float*)d_in[11];
    const float* bn2_v = (const float*)d_in[12];
    const float* c3_w = (const float*)d_in[13];
    const float* c3_b = (const float*)d_in[14];
    const float* bn3_g = (const float*)d_in[15];
    const float* bn3_b = (const float*)d_in[16];
    const float* bn3_m = (const float*)d_in[17];
    const float* bn3_v = (const float*)d_in[18];
    const float* fc_w = (const float*)d_in[19];
    const float* fc_b = (const float*)d_in[20];
    const float* wq = (const float*)d_in[21];
    const float* wk = (const float*)d_in[22];
    const float* wv = (const float*)d_in[23];
    const float* rel = (const float*)d_in[24];
    const float* ln_g = (const float*)d_in[25];
    const float* ln_b = (const float*)d_in[26];
    const float* lin_w = (const float*)d_in[27];
    const float* lin_b = (const float*)d_in[28];

    float* ws = (float*)d_ws;
    __hip_bfloat16* x3bf = (__hip_bfloat16*)ws;                 // 13.1M bf16
    __hip_bfloat16* wp_bf = (__hip_bfloat16*)(ws + 19000000);
    float* bp = ws + 19100000;
    float* Qb = ws + 23449600;
    float* attout = Qb + 3000000;

    float* frame_pred = (float*)d_out;
    float* a_out = frame_pred + (size_t)B_ * T_ * OF_;

    wprime_kernel<<<cdiv(144 * KP_ + 144, 256), 256, 0, stream>>>(fc_w, fc_b, wq, wk, wv,
                                                                  wp_bf, bp);
    conv123_kernel<<<dim3(T_ / TS_, B_), 640, 0, stream>>>(
        spec, c1_w, c1_b, bn1_g, bn1_b, bn1_m, bn1_v,
        c2_w, c2_b, bn2_g, bn2_b, bn2_m, bn2_v,
        c3_w, c3_b, bn3_g, bn3_b, bn3_m, bn3_v, x3bf);
    fc_qkv_mfma_kernel<<<960, 256, 0, stream>>>(x3bf, wp_bf, bp, Qb);
    attn_kernel<<<dim3(T_ / 32, B_), 256, 0, stream>>>(Qb, rel, attout, a_out);
    ln_kernel<<<(B_ * T_) / 32, 256, 0, stream>>>(attout, ln_g, ln_b, lin_w, lin_b,
                                                  frame_pred);
}

// Round 8
// 338.959 us; speedup vs baseline: 5.6407x; 1.0625x over previous
//
#include <hip/hip_runtime.h>
#include <hip/hip_bf16.h>
#include <math.h>

#define B_    8
#define T_    2560
#define F_    229
#define C1_   5
#define C2_   11
#define W1_   114
#define W2_   57
#define KP_   640
#define OF_   88
#define MC_   48
#define G_    8
#define DH_   6
#define K_    31
#define PAD_  15
#define BN_EPS 1e-5f
#define LN_EPS 1e-5f
#define TS_   8

typedef __attribute__((ext_vector_type(8))) short short8;
typedef __attribute__((ext_vector_type(4))) float f32x4;

static inline int cdiv(int a, int b) { return (a + b - 1) / b; }

__device__ inline float bflo(unsigned u) { return __uint_as_float(u << 16); }
__device__ inline float bfhi(unsigned u) { return __uint_as_float(u & 0xffff0000u); }

// ---- fused conv1+conv2+pool+conv3+pool: spec (B,T,229) -> x3bf [bt][640] ----
// x1 tile in bf16 (27.8 KB); spec tile (13 KB) unions with x2p tile; total
// ~44 KB LDS -> 3 blocks/CU (the 10-wave block caps at 3 anyway).
__global__ __launch_bounds__(640, 8) void conv123_kernel(
        const float* __restrict__ spec,
        const float* __restrict__ c1w, const float* __restrict__ c1b,
        const float* __restrict__ g1, const float* __restrict__ b1,
        const float* __restrict__ m1, const float* __restrict__ v1,
        const float* __restrict__ c2w, const float* __restrict__ c2b,
        const float* __restrict__ g2, const float* __restrict__ b2,
        const float* __restrict__ m2, const float* __restrict__ v2,
        const float* __restrict__ c3w, const float* __restrict__ c3b,
        const float* __restrict__ g3, const float* __restrict__ b3,
        const float* __restrict__ m3, const float* __restrict__ v3,
        __hip_bfloat16* __restrict__ x3out) {
    __shared__ ushort x1t[12 * 5 * 232];     // 27,840 B bf16 (col = f+1)
    __shared__ float specx2[14 * 232];       // 12,992 B: spec tile, then x2p bf16 tile
    __shared__ float w1s[45], w2s[225], w3s[495];
    __shared__ float scl1[5], shf1[5], scl2[5], shf2[5], scl3[11], shf3[11];
    int t0 = blockIdx.x * TS_;
    int b = blockIdx.y;
    int tid = threadIdx.x;

    if (tid < 45) w1s[tid] = c1w[tid];
    for (int i = tid; i < 225; i += 640) w2s[i] = c2w[i];
    for (int i = tid; i < 495; i += 640) w3s[i] = c3w[i];
    if (tid < 5) {
        float s = g1[tid] * rsqrtf(v1[tid] + BN_EPS);
        scl1[tid] = s;
        shf1[tid] = (c1b[tid] - m1[tid]) * s + b1[tid];
    }
    if (tid >= 64 && tid < 69) {
        int c = tid - 64;
        float s = g2[c] * rsqrtf(v2[c] + BN_EPS);
        scl2[c] = s;
        shf2[c] = (c2b[c] - m2[c]) * s + b2[c];
    }
    if (tid >= 128 && tid < 139) {
        int c = tid - 128;
        float s = g3[c] * rsqrtf(v3[c] + BN_EPS);
        scl3[c] = s;
        shf3[c] = (c3b[c] - m3[c]) * s + b3[c];
    }
    // stage spec rows t0-3 .. t0+10 (zero-padded), col = f+1
    {
        const float* sb = spec + (size_t)b * T_ * F_;
        for (int i = tid; i < 14 * 232; i += 640) {
            int col = i % 232;
            int rr = i / 232;
            int t = t0 - 3 + rr;
            int f = col - 1;
            float v = 0.f;
            if (t >= 0 && t < T_ && f >= 0 && f < F_) v = sb[(size_t)t * F_ + f];
            specx2[i] = v;
        }
    }
    __syncthreads();

    // ---- phase 1: conv1+bn+relu -> x1t rows t0-2..t0+9 (bf16) ----
    for (int i = tid; i < 12 * 229; i += 640) {
        int f = i % 229;
        int rr = i / 229;
        int t = t0 - 2 + rr;
        float y[5];
        if (t >= 0 && t < T_) {
            float tp[9];
#pragma unroll
            for (int dt = 0; dt < 3; ++dt) {
                const float* row = &specx2[(rr + dt) * 232 + f];
                tp[dt * 3 + 0] = row[0];
                tp[dt * 3 + 1] = row[1];
                tp[dt * 3 + 2] = row[2];
            }
#pragma unroll
            for (int co = 0; co < 5; ++co) {
                float acc = 0.f;
#pragma unroll
                for (int k = 0; k < 9; ++k) acc = fmaf(tp[k], w1s[co * 9 + k], acc);
                y[co] = fmaxf(fmaf(acc, scl1[co], shf1[co]), 0.f);
            }
        } else {
#pragma unroll
            for (int co = 0; co < 5; ++co) y[co] = 0.f;
        }
#pragma unroll
        for (int co = 0; co < 5; ++co) {
            __hip_bfloat16 h = __float2bfloat16(y[co]);
            x1t[(rr * 5 + co) * 232 + 1 + f] = *(ushort*)&h;
        }
    }
    for (int i = tid; i < 180; i += 640) {
        int c = i % 3;
        int col = (c == 0) ? 0 : 229 + c;
        int ci = (i / 3) % 5;
        int rr = i / 15;
        x1t[(rr * 5 + ci) * 232 + col] = 0;
    }
    __syncthreads();

    // ---- phase 2: conv2+bn+relu+pool -> x2pt (bf16, unions with spec tile) ----
    ushort* x2pt = (ushort*)specx2;          // 10 rows x 5 ci x 120 (col = w+1)
    if (tid < 570) {
        int co = tid / 114;
        int j = tid % 114;
        float acc0[10], acc1[10];
#pragma unroll
        for (int r = 0; r < 10; ++r) { acc0[r] = 0.f; acc1[r] = 0.f; }
#pragma unroll
        for (int ci = 0; ci < 5; ++ci) {
            float wr[9];
#pragma unroll
            for (int k = 0; k < 9; ++k) wr[k] = w2s[(co * 5 + ci) * 9 + k];
#pragma unroll
            for (int rr = 0; rr < 12; ++rr) {
                const ushort* p = &x1t[(rr * 5 + ci) * 232 + 2 * j];
                unsigned u0 = *(const unsigned*)p;
                unsigned u1 = *(const unsigned*)(p + 2);
                float v0 = bflo(u0), v1 = bfhi(u0), v2_ = bflo(u1), v3_ = bfhi(u1);
#pragma unroll
                for (int dt = 0; dt < 3; ++dt) {
                    int r = rr - dt;
                    if (r >= 0 && r < 10) {
                        acc0[r] = fmaf(v0, wr[dt * 3],
                                  fmaf(v1, wr[dt * 3 + 1],
                                  fmaf(v2_, wr[dt * 3 + 2], acc0[r])));
                        acc1[r] = fmaf(v1, wr[dt * 3],
                                  fmaf(v2_, wr[dt * 3 + 1],
                                  fmaf(v3_, wr[dt * 3 + 2], acc1[r])));
                    }
                }
            }
        }
        float s = scl2[co], sh = shf2[co];
        float yv[10];
#pragma unroll
        for (int r = 0; r < 10; ++r) {
            int t = t0 - 1 + r;
            float y = fmaxf(fmaxf(acc0[r] * s + sh, 0.f), fmaxf(acc1[r] * s + sh, 0.f));
            yv[r] = (t < 0 || t >= T_) ? 0.f : y;
        }
        __syncthreads();                      // spec tile dead; safe to overwrite
#pragma unroll
        for (int r = 0; r < 10; ++r) {
            __hip_bfloat16 h = __float2bfloat16(yv[r]);
            x2pt[(r * 5 + co) * 120 + 1 + j] = *(ushort*)&h;
        }
    } else {
        __syncthreads();
        for (int i = tid - 570; i < 300; i += 70) {
            int cc = i % 6;
            int col = (cc == 0) ? 0 : 114 + cc;
            int ci = (i / 6) % 5;
            int r = i / 30;
            x2pt[(r * 5 + ci) * 120 + col] = 0;
        }
    }
    __syncthreads();

    // ---- phase 3: conv3+bn+relu+pool -> x3out bf16 [bt][640] ----
    if (tid < 627) {
        int co = tid / 57;
        int j = tid % 57;
        float acc0[8], acc1[8];
#pragma unroll
        for (int r = 0; r < 8; ++r) { acc0[r] = 0.f; acc1[r] = 0.f; }
#pragma unroll
        for (int ci = 0; ci < 5; ++ci) {
            float wr[9];
#pragma unroll
            for (int k = 0; k < 9; ++k) wr[k] = w3s[(co * 5 + ci) * 9 + k];
#pragma unroll
            for (int rr = 0; rr < 10; ++rr) {
                const ushort* p = &x2pt[(rr * 5 + ci) * 120 + 2 * j];
                unsigned u0 = *(const unsigned*)p;
                unsigned u1 = *(const unsigned*)(p + 2);
                float v0 = bflo(u0), v1 = bfhi(u0), v2_ = bflo(u1), v3_ = bfhi(u1);
#pragma unroll
                for (int dt = 0; dt < 3; ++dt) {
                    int r = rr - dt;
                    if (r >= 0 && r < 8) {
                        acc0[r] = fmaf(v0, wr[dt * 3],
                                  fmaf(v1, wr[dt * 3 + 1],
                                  fmaf(v2_, wr[dt * 3 + 2], acc0[r])));
                        acc1[r] = fmaf(v1, wr[dt * 3],
                                  fmaf(v2_, wr[dt * 3 + 1],
                                  fmaf(v3_, wr[dt * 3 + 2], acc1[r])));
                    }
                }
            }
        }
        float s = scl3[co], sh = shf3[co];
#pragma unroll
        for (int r = 0; r < 8; ++r) {
            float y0 = fmaxf(acc0[r] * s + sh, 0.f);
            float y1 = fmaxf(acc1[r] * s + sh, 0.f);
            x3out[(size_t)(b * T_ + t0 + r) * KP_ + co * 57 + j] =
                __float2bfloat16(fmaxf(y0, y1));
        }
    } else if (tid >= 627 && tid < 640) {
        __hip_bfloat16 z = __float2bfloat16(0.f);
#pragma unroll
        for (int r = 0; r < 8; ++r)
            x3out[(size_t)(b * T_ + t0 + r) * KP_ + tid] = z;
    }
}

// -------- W' = [wq;wk;wv] @ fc_w -> bf16 [144][640] (padded), b' fp32 --------
__global__ __launch_bounds__(256) void wprime_kernel(const float* __restrict__ fc_w,
        const float* __restrict__ fc_b, const float* __restrict__ wq,
        const float* __restrict__ wk, const float* __restrict__ wv,
        __hip_bfloat16* __restrict__ wp, float* __restrict__ bp) {
    int idx = blockIdx.x * 256 + threadIdx.x;
    if (idx < 144 * KP_) {
        int o = idx / KP_;
        int kk = idx % KP_;
        const float* Wrow = (o < 48) ? (wq + o * 88)
                          : (o < 96) ? (wk + (o - 48) * 88) : (wv + (o - 96) * 88);
        float s = 0.f;
        if (kk < 627)
            for (int i = 0; i < 88; ++i) s = fmaf(Wrow[i], fc_w[(size_t)i * 627 + kk], s);
        wp[idx] = __float2bfloat16(s);
    } else if (idx < 144 * KP_ + 144) {
        int o = idx - 144 * KP_;
        const float* Wrow = (o < 48) ? (wq + o * 88)
                          : (o < 96) ? (wk + (o - 48) * 88) : (wv + (o - 96) * 88);
        float s = 0.f;
        for (int i = 0; i < 88; ++i) s = fmaf(Wrow[i], fc_b[i], s);
        bp[o] = s;
    }
}

// -------- fused FC+QKV via MFMA bf16: Q[bt][144] = X[bt][640] @ W'^T + b' --------
__global__ __launch_bounds__(256) void fc_qkv_mfma_kernel(
        const __hip_bfloat16* __restrict__ X, const __hip_bfloat16* __restrict__ Wp,
        const float* __restrict__ bp, float* __restrict__ Q) {
    int tid = threadIdx.x;
    int lane = tid & 63;
    int gw = blockIdx.x * 4 + (tid >> 6);
    int mtile = gw / 3;
    int nthird = gw % 3;
    const short* Xs = (const short*)X;
    const short* Ws = (const short*)Wp;
    int klane = (lane >> 4) * 8;
    const short* xrow = Xs + (size_t)(mtile * 16 + (lane & 15)) * KP_ + klane;
    const short* wrow = Ws + (size_t)(nthird * 48 + (lane & 15)) * KP_ + klane;
    f32x4 acc0 = {0.f, 0.f, 0.f, 0.f}, acc1 = acc0, acc2 = acc0;
#pragma unroll 4
    for (int kt = 0; kt < 20; ++kt) {
        short8 a = *(const short8*)(xrow + kt * 32);
        short8 b0 = *(const short8*)(wrow + kt * 32);
        short8 b1 = *(const short8*)(wrow + 16 * KP_ + kt * 32);
        short8 b2 = *(const short8*)(wrow + 32 * KP_ + kt * 32);
        acc0 = __builtin_amdgcn_mfma_f32_16x16x32_bf16(a, b0, acc0, 0, 0, 0);
        acc1 = __builtin_amdgcn_mfma_f32_16x16x32_bf16(a, b1, acc1, 0, 0, 0);
        acc2 = __builtin_amdgcn_mfma_f32_16x16x32_bf16(a, b2, acc2, 0, 0, 0);
    }
    int r0 = mtile * 16 + (lane >> 4) * 4;
    int col = lane & 15;
    f32x4 accs[3] = {acc0, acc1, acc2};
#pragma unroll
    for (int nt = 0; nt < 3; ++nt) {
        int o = nthird * 48 + nt * 16 + col;
        float bias = bp[o];
#pragma unroll
        for (int rg = 0; rg < 4; ++rg)
            Q[(size_t)(r0 + rg) * 144 + o] = accs[nt][rg] + bias;
    }
}

// ----- windowed relative attention + LayerNorm + linear + sigmoid, fused -----
// 32-t tile per block; a written coalesced via LDS; attout never leaves LDS.
__global__ __launch_bounds__(256) void attn_ln_kernel(const float* __restrict__ Q,
        const float* __restrict__ rel, const float* __restrict__ lng,
        const float* __restrict__ lnb, const float* __restrict__ lw,
        const float* __restrict__ lb, float* __restrict__ fp,
        float* __restrict__ aout) {
    __shared__ float smem[9472];     // kvt[0,6200) qt[6200,7864) relT[7864,9352)
                                     // reuse: abuf[0,7936) xr[7936,9472)
    __shared__ float mus[32], rss[32];
    float* kvt = smem;
    float* qt = smem + 6200;
    float* relT = smem + 7864;
    int b = blockIdx.y;
    int t0 = blockIdx.x * 32;
    int tid = threadIdx.x;
    for (int i = tid; i < 62 * 48; i += 256) {
        int row = i / 48, c2 = i % 48;
        int t = t0 - 15 + row;
        float2 v = {0.f, 0.f};
        if (t >= 0 && t < T_)
            v = *(const float2*)&Q[((size_t)b * T_ + t) * 144 + 48 + 2 * c2];
        *(float2*)&kvt[row * 100 + 2 * c2] = v;
    }
    for (int i = tid; i < 32 * 24; i += 256) {
        int row = i / 24, c2 = i % 24;
        float2 v = *(const float2*)&Q[((size_t)b * T_ + t0 + row) * 144 + 2 * c2];
        *(float2*)&qt[row * 52 + 2 * c2] = v;
    }
    for (int i = tid; i < 31 * 48; i += 256) {
        int kp = i / 48, j = i % 48;
        relT[i] = rel[j * 31 + kp];
    }
    __syncthreads();
    int g = tid & 7;
    int tl = tid >> 3;
    const float* qp = &qt[tl * 52 + g * 6];
    float2 q01 = *(const float2*)qp;
    float2 q23 = *(const float2*)(qp + 2);
    float2 q45 = *(const float2*)(qp + 4);
    float e[31];
    float emax = -1e30f;
#pragma unroll
    for (int kp = 0; kp < 31; ++kp) {
        const float* kr = &kvt[(tl + kp) * 100 + g * 6];
        const float* rr = &relT[kp * 48 + g * 6];
        float2 k01 = *(const float2*)kr;
        float2 k23 = *(const float2*)(kr + 2);
        float2 k45 = *(const float2*)(kr + 4);
        float2 r01 = *(const float2*)rr;
        float2 r23 = *(const float2*)(rr + 2);
        float2 r45 = *(const float2*)(rr + 4);
        float s = fmaf(q01.x, k01.x + r01.x,
                  fmaf(q01.y, k01.y + r01.y,
                  fmaf(q23.x, k23.x + r23.x,
                  fmaf(q23.y, k23.y + r23.y,
                  fmaf(q45.x, k45.x + r45.x,
                       q45.y * (k45.y + r45.y))))));
        e[kp] = s;
        emax = fmaxf(emax, s);
    }
    float sum = 0.f;
#pragma unroll
    for (int kp = 0; kp < 31; ++kp) { e[kp] = __expf(e[kp] - emax); sum += e[kp]; }
    float inv = 1.f / sum;
    float o0 = 0, o1 = 0, o2 = 0, o3 = 0, o4 = 0, o5 = 0;
#pragma unroll
    for (int kp = 0; kp < 31; ++kp) {
        float a = e[kp] * inv;
        e[kp] = a;
        const float* vr = &kvt[(tl + kp) * 100 + 48 + g * 6];
        float2 v01 = *(const float2*)vr;
        float2 v23 = *(const float2*)(vr + 2);
        float2 v45 = *(const float2*)(vr + 4);
        o0 = fmaf(a, v01.x, o0); o1 = fmaf(a, v01.y, o1);
        o2 = fmaf(a, v23.x, o2); o3 = fmaf(a, v23.y, o3);
        o4 = fmaf(a, v45.x, o4); o5 = fmaf(a, v45.y, o5);
    }
    __syncthreads();                 // all LDS reads done; reuse regions
    float* abuf = smem;              // 256 x 31
    float* xr = smem + 7936;         // 32 x 48
#pragma unroll
    for (int kp = 0; kp < 31; ++kp) abuf[tid * 31 + kp] = e[kp];
    {
        float* xp = &xr[tl * 48 + g * 6];
        xp[0] = o0; xp[1] = o1; xp[2] = o2; xp[3] = o3; xp[4] = o4; xp[5] = o5;
    }
    __syncthreads();
    // coalesced a-writes
    size_t base = ((size_t)b * T_ + t0) * 248;
    for (int i = tid; i < 1984; i += 256) {
        float4 v = *(const float4*)&abuf[4 * i];
        *(float4*)&aout[base + 4 * i] = v;
    }
    // LN stats
    if (tid < 32) {
        const float* row = &xr[tid * 48];
        float s = 0.f;
        for (int c = 0; c < 48; ++c) s += row[c];
        float mu = s * (1.f / 48.f);
        float v2 = 0.f;
        for (int c = 0; c < 48; ++c) { float d = row[c] - mu; v2 = fmaf(d, d, v2); }
        mus[tid] = mu;
        rss[tid] = rsqrtf(v2 * (1.f / 48.f) + LN_EPS);
    }
    __syncthreads();
    // normalize xr in place
    for (int i = tid; i < 1536; i += 256) {
        int r = i / 48, c = i % 48;
        xr[i] = fmaf((xr[i] - mus[r]) * rss[r], lng[c], lnb[c]);
    }
    __syncthreads();
    // linear 48->88 + sigmoid
    size_t obase = ((size_t)b * T_ + t0) * 88;
    for (int k = 0; k < 11; ++k) {
        int cid = k * 256 + tid;
        int o = cid % 88, r = cid / 88;
        const float* xp = &xr[r * 48];
        const float* wpp = &lw[o * 48];
        float s = lb[o];
#pragma unroll
        for (int c = 0; c < 48; c += 4) {
            float4 xv = *(const float4*)&xp[c];
            float4 wv = *(const float4*)&wpp[c];
            s = fmaf(xv.x, wv.x, s);
            s = fmaf(xv.y, wv.y, s);
            s = fmaf(xv.z, wv.z, s);
            s = fmaf(xv.w, wv.w, s);
        }
        fp[obase + cid] = 1.f / (1.f + __expf(-s));
    }
}

extern "C" void kernel_launch(void* const* d_in, const int* in_sizes, int n_in,
                              void* d_out, int out_size, void* d_ws, size_t ws_size,
                              hipStream_t stream) {
    const float* spec = (const float*)d_in[0];
    const float* c1_w = (const float*)d_in[1];
    const float* c1_b = (const float*)d_in[2];
    const float* bn1_g = (const float*)d_in[3];
    const float* bn1_b = (const float*)d_in[4];
    const float* bn1_m = (const float*)d_in[5];
    const float* bn1_v = (const float*)d_in[6];
    const float* c2_w = (const float*)d_in[7];
    const float* c2_b = (const float*)d_in[8];
    const float* bn2_g = (const float*)d_in[9];
    const float* bn2_b = (const float*)d_in[10];
    const float* bn2_m = (const float*)d_in[11];
    const float* bn2_v = (const float*)d_in[12];
    const float* c3_w = (const float*)d_in[13];
    const float* c3_b = (const float*)d_in[14];
    const float* bn3_g = (const float*)d_in[15];
    const float* bn3_b = (const float*)d_in[16];
    const float* bn3_m = (const float*)d_in[17];
    const float* bn3_v = (const float*)d_in[18];
    const float* fc_w = (const float*)d_in[19];
    const float* fc_b = (const float*)d_in[20];
    const float* wq = (const float*)d_in[21];
    const float* wk = (const float*)d_in[22];
    const float* wv = (const float*)d_in[23];
    const float* rel = (const float*)d_in[24];
    const float* ln_g = (const float*)d_in[25];
    const float* ln_b = (const float*)d_in[26];
    const float* lin_w = (const float*)d_in[27];
    const float* lin_b = (const float*)d_in[28];

    float* ws = (float*)d_ws;
    __hip_bfloat16* x3bf = (__hip_bfloat16*)ws;                 // 13.1M bf16
    __hip_bfloat16* wp_bf = (__hip_bfloat16*)(ws + 19000000);
    float* bp = ws + 19100000;
    float* Qb = ws + 23449600;

    float* frame_pred = (float*)d_out;
    float* a_out = frame_pred + (size_t)B_ * T_ * OF_;

    wprime_kernel<<<cdiv(144 * KP_ + 144, 256), 256, 0, stream>>>(fc_w, fc_b, wq, wk, wv,
                                                                  wp_bf, bp);
    conv123_kernel<<<dim3(T_ / TS_, B_), 640, 0, stream>>>(
        spec, c1_w, c1_b, bn1_g, bn1_b, bn1_m, bn1_v,
        c2_w, c2_b, bn2_g, bn2_b, bn2_m, bn2_v,
        c3_w, c3_b, bn3_g, bn3_b, bn3_m, bn3_v, x3bf);
    fc_qkv_mfma_kernel<<<960, 256, 0, stream>>>(x3bf, wp_bf, bp, Qb);
    attn_ln_kernel<<<dim3(T_ / 32, B_), 256, 0, stream>>>(Qb, rel, ln_g, ln_b, lin_w,
                                                          lin_b, frame_pred, a_out);
}